// Round 1
// baseline (873.496 us; speedup 1.0000x reference)
//
#include <hip/hip_runtime.h>
#include <math.h>

#define N_ 8
#define F_ 64
#define P_ 25
#define H_ 6
#define D_ 192
#define HD_ 32
#define T_ 1600
#define SCALE_ 0.17677669529663687f

// ---------------------------------------------------------------------------
// Kernel 0: evaluate the two bias MLPs into workspace tables.
// table_t: [H][127]  (temporal, rel frame offset -63..63)
// table_h: [H][5]    (hop values 0..4)
// grid: 132 blocks (127 temporal coords + 5 hop coords), 192 threads
// ---------------------------------------------------------------------------
__global__ void bias_tables_kernel(
    const float* __restrict__ t_w1, const float* __restrict__ t_b1,
    const float* __restrict__ t_w2, const float* __restrict__ t_b2,
    const float* __restrict__ h_w1, const float* __restrict__ h_b1,
    const float* __restrict__ h_w2, const float* __restrict__ h_b2,
    float* __restrict__ tt, float* __restrict__ th)
{
    __shared__ float hid[192];
    int b = blockIdx.x;
    bool is_t = (b < 127);
    float pos = is_t ? (float)(b - 63) : (float)(b - 127);
    const float* w1 = is_t ? t_w1 : h_w1;
    const float* b1 = is_t ? t_b1 : h_b1;
    const float* w2 = is_t ? t_w2 : h_w2;
    const float* b2 = is_t ? t_b2 : h_b2;
    int t = threadIdx.x;
    if (t < 192) hid[t] = fmaxf(pos * w1[t] + b1[t], 0.0f);
    __syncthreads();
    if (t < 6) {
        float s = b2[t];
        for (int j = 0; j < 192; ++j) s += w2[t * 192 + j] * hid[j];
        if (is_t) tt[t * 127 + b] = s;
        else      th[t * 5 + (b - 127)] = s;
    }
}

// ---------------------------------------------------------------------------
// Kernel 1: QKV projection GEMM.  C[12800][576] = X[12800][192] @ W[576][192]^T
// scattered into q/k/v buffers laid out (N,H,T,HD).
// Block: 256 threads = 16x16, each computes a 4x4 micro-tile of a 64x64 tile.
// grid: 200 row-tiles * 9 col-tiles = 1800 blocks
// ---------------------------------------------------------------------------
__global__ __launch_bounds__(256) void qkv_kernel(
    const float* __restrict__ x, const float* __restrict__ w,
    float* __restrict__ qout, float* __restrict__ kout, float* __restrict__ vout)
{
    __shared__ float xs[64][33];
    __shared__ float wsh[64][33];
    int bm = blockIdx.x % 200;
    int bn = blockIdx.x / 200;
    int row0 = bm * 64, col0 = bn * 64;
    int tid = threadIdx.x;
    int ty = tid >> 4, tx = tid & 15;

    float acc[4][4];
    #pragma unroll
    for (int i = 0; i < 4; ++i)
        #pragma unroll
        for (int j = 0; j < 4; ++j) acc[i][j] = 0.0f;

    for (int k0 = 0; k0 < 192; k0 += 32) {
        __syncthreads();
        #pragma unroll
        for (int p = 0; p < 2; ++p) {
            int fid = tid + p * 256;
            int r = fid >> 3, ch = fid & 7;
            float4 a4 = *(const float4*)&x[(size_t)(row0 + r) * 192 + k0 + ch * 4];
            xs[r][ch * 4 + 0] = a4.x; xs[r][ch * 4 + 1] = a4.y;
            xs[r][ch * 4 + 2] = a4.z; xs[r][ch * 4 + 3] = a4.w;
            float4 b4 = *(const float4*)&w[(size_t)(col0 + r) * 192 + k0 + ch * 4];
            wsh[r][ch * 4 + 0] = b4.x; wsh[r][ch * 4 + 1] = b4.y;
            wsh[r][ch * 4 + 2] = b4.z; wsh[r][ch * 4 + 3] = b4.w;
        }
        __syncthreads();
        #pragma unroll
        for (int kk = 0; kk < 32; ++kk) {
            float a[4], b[4];
            #pragma unroll
            for (int i = 0; i < 4; ++i) a[i] = xs[ty * 4 + i][kk];
            #pragma unroll
            for (int j = 0; j < 4; ++j) b[j] = wsh[tx * 4 + j][kk];
            #pragma unroll
            for (int i = 0; i < 4; ++i)
                #pragma unroll
                for (int j = 0; j < 4; ++j) acc[i][j] += a[i] * b[j];
        }
    }

    #pragma unroll
    for (int i = 0; i < 4; ++i) {
        int rr = row0 + ty * 4 + i;
        int n = rr / 1600, t = rr % 1600;
        #pragma unroll
        for (int j = 0; j < 4; ++j) {
            int cc = col0 + tx * 4 + j;
            int three = cc / 192;
            int rem = cc - three * 192;
            int h = rem >> 5, c = rem & 31;
            float* dst = (three == 0) ? qout : ((three == 1) ? kout : vout);
            dst[(size_t)((n * 6 + h) * 1600 + t) * 32 + c] = acc[i][j];
        }
    }
}

// ---------------------------------------------------------------------------
// Kernel 2: fused attention with online softmax + bias tables.
// Block: 256 threads (4 waves). Block handles (n, h, 8 consecutive t rows);
// each wave owns 2 rows. K/V staged per 64-s tile in LDS (stride 33, 2-way
// bank aliasing = free). Lane owns one s per tile; per-lane partial PV
// accumulators, reduced via padded LDS scratch at the end.
// grid: N*H*(T/8) = 9600 blocks
// ---------------------------------------------------------------------------
__device__ __forceinline__ void attn_epilogue(
    float (&acc)[32], float lpart, int tglob, float alpha,
    float (*scrw)[33], float* __restrict__ aout_base, int lane)
{
    float L = lpart;
    #pragma unroll
    for (int off = 32; off >= 1; off >>= 1) L += __shfl_xor(L, off, 64);
    #pragma unroll
    for (int c = 0; c < 32; ++c) scrw[lane][c] = acc[c];
    __asm__ volatile("s_waitcnt lgkmcnt(0)" ::: "memory");
    int c = lane & 31, half = lane >> 5;
    float ssum = 0.0f;
    #pragma unroll
    for (int rr = 0; rr < 32; ++rr) ssum += scrw[half * 32 + rr][c];
    ssum += __shfl_xor(ssum, 32, 64);
    if (lane < 32) aout_base[(size_t)tglob * 32 + c] = alpha * ssum / L;
    __asm__ volatile("s_waitcnt lgkmcnt(0)" ::: "memory");
}

__global__ __launch_bounds__(256) void attn_kernel(
    const float* __restrict__ qw, const float* __restrict__ kw,
    const float* __restrict__ vw, const float* __restrict__ tt,
    const float* __restrict__ th, const int* __restrict__ hops,
    const float* __restrict__ alpha_p, float* __restrict__ aout)
{
    __shared__ float ks[64][33];
    __shared__ float vs[64][33];
    __shared__ float scr[4][64][33];
    __shared__ float ttl[128];
    __shared__ float hbl[640];
    __shared__ float qs[8][32];

    int blk = blockIdx.x;
    int rt = blk % 200;
    int h  = (blk / 200) % 6;
    int n  = blk / 1200;
    int t0 = rt * 8;
    int tid = threadIdx.x;
    int lane = tid & 63;
    int wv = tid >> 6;

    const float* qb = qw + (size_t)((n * 6 + h) * 1600) * 32;
    const float* kb = kw + (size_t)((n * 6 + h) * 1600) * 32;
    const float* vb = vw + (size_t)((n * 6 + h) * 1600) * 32;
    float* ab = aout + (size_t)((n * 6 + h) * 1600) * 32;

    if (tid < 127) ttl[tid] = tt[h * 127 + tid];
    for (int i = tid; i < 625; i += 256) hbl[i] = th[h * 5 + hops[i]];
    { int r = tid >> 5, c = tid & 31; qs[r][c] = qb[(size_t)(t0 + r) * 32 + c]; }
    __syncthreads();

    float qr0[32], qr1[32];
    int tg0 = t0 + wv * 2, tg1 = t0 + wv * 2 + 1;
    int ft0 = tg0 / 25, pt0 = tg0 - ft0 * 25;
    int ft1 = tg1 / 25, pt1 = tg1 - ft1 * 25;
    #pragma unroll
    for (int c = 0; c < 32; ++c) { qr0[c] = qs[wv * 2][c]; qr1[c] = qs[wv * 2 + 1][c]; }

    float m0 = -1e30f, m1 = -1e30f, l0 = 0.0f, l1 = 0.0f;
    float acc0[32], acc1[32];
    #pragma unroll
    for (int c = 0; c < 32; ++c) { acc0[c] = 0.0f; acc1[c] = 0.0f; }

    for (int s0 = 0; s0 < 1600; s0 += 64) {
        __syncthreads();
        #pragma unroll
        for (int p = 0; p < 2; ++p) {
            int fid = tid + p * 256;
            int r = fid >> 3, ch = fid & 7;
            float4 k4 = *(const float4*)&kb[(size_t)(s0 + r) * 32 + ch * 4];
            ks[r][ch * 4 + 0] = k4.x; ks[r][ch * 4 + 1] = k4.y;
            ks[r][ch * 4 + 2] = k4.z; ks[r][ch * 4 + 3] = k4.w;
            float4 v4 = *(const float4*)&vb[(size_t)(s0 + r) * 32 + ch * 4];
            vs[r][ch * 4 + 0] = v4.x; vs[r][ch * 4 + 1] = v4.y;
            vs[r][ch * 4 + 2] = v4.z; vs[r][ch * 4 + 3] = v4.w;
        }
        __syncthreads();

        int s = s0 + lane;
        int fs = s / 25;
        int ps = s - fs * 25;

        float d0 = 0.0f, d1 = 0.0f;
        #pragma unroll
        for (int c = 0; c < 32; ++c) {
            float kc = ks[lane][c];
            d0 += kc * qr0[c];
            d1 += kc * qr1[c];
        }
        float lg0 = (d0 + ttl[ft0 - fs + 63] + hbl[pt0 * 25 + ps]) * SCALE_;
        float lg1 = (d1 + ttl[ft1 - fs + 63] + hbl[pt1 * 25 + ps]) * SCALE_;

        float tm0 = lg0, tm1 = lg1;
        #pragma unroll
        for (int off = 32; off >= 1; off >>= 1) {
            tm0 = fmaxf(tm0, __shfl_xor(tm0, off, 64));
            tm1 = fmaxf(tm1, __shfl_xor(tm1, off, 64));
        }
        if (tm0 > m0) {
            float sc = __expf(m0 - tm0);
            l0 *= sc;
            #pragma unroll
            for (int c = 0; c < 32; ++c) acc0[c] *= sc;
            m0 = tm0;
        }
        if (tm1 > m1) {
            float sc = __expf(m1 - tm1);
            l1 *= sc;
            #pragma unroll
            for (int c = 0; c < 32; ++c) acc1[c] *= sc;
            m1 = tm1;
        }
        float p0 = __expf(lg0 - m0);
        float p1 = __expf(lg1 - m1);
        l0 += p0; l1 += p1;
        #pragma unroll
        for (int c = 0; c < 32; ++c) {
            float vc = vs[lane][c];
            acc0[c] += p0 * vc;
            acc1[c] += p1 * vc;
        }
    }

    float alpha = alpha_p[0];
    attn_epilogue(acc0, l0, tg0, alpha, scr[wv], ab, lane);
    attn_epilogue(acc1, l1, tg1, alpha, scr[wv], ab, lane);
}

// ---------------------------------------------------------------------------
// Kernel 3: fuse relational (outer) term and final projection.
// Block handles (n, 16 consecutive t rows). Phase A builds combined[16][192]
// (attn_out + outer term); Phase B is a K-tiled 192x192 projection GEMM.
// grid: N*T/16 = 800 blocks, 256 threads
// ---------------------------------------------------------------------------
__global__ __launch_bounds__(256) void proj_kernel(
    const float* __restrict__ ao, const float* __restrict__ vw,
    const float* __restrict__ outer, const float* __restrict__ pw,
    const float* __restrict__ pb, float* __restrict__ out)
{
    __shared__ float comb[16][193];
    __shared__ float wsh[192][33];
    int blk = blockIdx.x;
    int n = blk / 100;
    int t0 = (blk % 100) * 16;
    int tid = threadIdx.x;

    for (int e = tid; e < 16 * 192; e += 256) {
        int r = e / 192;
        int j = e - r * 192;
        int t = t0 + r;
        int hh = j >> 5, c = j & 31;
        int ftt = t / 25;
        int ptt = t - ftt * 25;
        const float* vrow = vw + (size_t)((n * 6 + hh) * 1600 + ftt * 25) * 32 + c;
        const float* orow = outer + hh * 625 + ptt * 25;
        float s = ao[(size_t)((n * 6 + hh) * 1600 + t) * 32 + c];
        #pragma unroll
        for (int q = 0; q < 25; ++q) s += orow[q] * vrow[q * 32];
        comb[r][j] = s;
    }

    int ty = tid >> 4, tx = tid & 15;
    float accp[12];
    #pragma unroll
    for (int jj = 0; jj < 12; ++jj) accp[jj] = 0.0f;

    for (int k0 = 0; k0 < 192; k0 += 32) {
        __syncthreads();
        #pragma unroll
        for (int p = 0; p < 6; ++p) {
            int fid = tid + p * 256;
            int j = fid >> 3, ch = fid & 7;
            float4 w4 = *(const float4*)&pw[(size_t)j * 192 + k0 + ch * 4];
            wsh[j][ch * 4 + 0] = w4.x; wsh[j][ch * 4 + 1] = w4.y;
            wsh[j][ch * 4 + 2] = w4.z; wsh[j][ch * 4 + 3] = w4.w;
        }
        __syncthreads();
        #pragma unroll
        for (int kk = 0; kk < 32; ++kk) {
            float a = comb[ty][k0 + kk];
            #pragma unroll
            for (int jj = 0; jj < 12; ++jj) accp[jj] += a * wsh[tx + 16 * jj][kk];
        }
    }

    #pragma unroll
    for (int jj = 0; jj < 12; ++jj) {
        int j = tx + 16 * jj;
        out[(size_t)(n * 1600 + t0 + ty) * 192 + j] = accp[jj] + pb[j];
    }
}

// ---------------------------------------------------------------------------
extern "C" void kernel_launch(void* const* d_in, const int* in_sizes, int n_in,
                              void* d_out, int out_size, void* d_ws, size_t ws_size,
                              hipStream_t stream)
{
    const float* x      = (const float*)d_in[0];
    const float* qkv_w  = (const float*)d_in[1];
    const float* proj_w = (const float*)d_in[2];
    const float* proj_b = (const float*)d_in[3];
    const float* t_w1   = (const float*)d_in[4];
    const float* t_b1   = (const float*)d_in[5];
    const float* t_w2   = (const float*)d_in[6];
    const float* t_b2   = (const float*)d_in[7];
    const float* h_w1   = (const float*)d_in[8];
    const float* h_b1   = (const float*)d_in[9];
    const float* h_w2   = (const float*)d_in[10];
    const float* h_b2   = (const float*)d_in[11];
    const float* outer  = (const float*)d_in[12];
    const float* alpha  = (const float*)d_in[13];
    const int*   hops   = (const int*)d_in[14];
    float* out = (float*)d_out;

    float* ws = (float*)d_ws;
    float* tt = ws;                      // 6*127 = 762
    float* th = ws + 762;                // 30
    float* qb = ws + 1024;               // 2457600 each
    float* kb = qb + 2457600;
    float* vb = kb + 2457600;
    float* ab = vb + 2457600;

    bias_tables_kernel<<<132, 192, 0, stream>>>(t_w1, t_b1, t_w2, t_b2,
                                                h_w1, h_b1, h_w2, h_b2, tt, th);
    qkv_kernel<<<1800, 256, 0, stream>>>(x, qkv_w, qb, kb, vb);
    attn_kernel<<<9600, 256, 0, stream>>>(qb, kb, vb, tt, th, hops, alpha, ab);
    proj_kernel<<<800, 256, 0, stream>>>(ab, vb, outer, proj_w, proj_b, out);
}

// Round 4
// 322.291 us; speedup vs baseline: 2.7103x; 2.7103x over previous
//
#include <hip/hip_runtime.h>
#include <math.h>

#define N_ 8
#define F_ 64
#define P_ 25
#define H_ 6
#define D_ 192
#define HD_ 32
#define T_ 1600
#define SCALE_ 0.17677669529663687f

typedef short bf16x8 __attribute__((ext_vector_type(8)));
typedef float f32x4 __attribute__((ext_vector_type(4)));
typedef unsigned int uint4v __attribute__((ext_vector_type(4)));

__device__ __forceinline__ unsigned short f2bf(float f) {
    unsigned int u = __float_as_uint(f);
    u += 0x7fffu + ((u >> 16) & 1u);
    return (unsigned short)(u >> 16);
}
__device__ __forceinline__ float bf2f(unsigned short s) {
    return __uint_as_float(((unsigned int)s) << 16);
}
__device__ __forceinline__ unsigned int pack2bf(float lo, float hi) {
    return (unsigned int)f2bf(lo) | ((unsigned int)f2bf(hi) << 16);
}

// ---------------------------------------------------------------------------
// Kernel 0: evaluate the two bias MLPs into workspace tables.
// ---------------------------------------------------------------------------
__global__ void bias_tables_kernel(
    const float* __restrict__ t_w1, const float* __restrict__ t_b1,
    const float* __restrict__ t_w2, const float* __restrict__ t_b2,
    const float* __restrict__ h_w1, const float* __restrict__ h_b1,
    const float* __restrict__ h_w2, const float* __restrict__ h_b2,
    float* __restrict__ tt, float* __restrict__ th)
{
    __shared__ float hid[192];
    int b = blockIdx.x;
    bool is_t = (b < 127);
    float pos = is_t ? (float)(b - 63) : (float)(b - 127);
    const float* w1 = is_t ? t_w1 : h_w1;
    const float* b1 = is_t ? t_b1 : h_b1;
    const float* w2 = is_t ? t_w2 : h_w2;
    const float* b2 = is_t ? t_b2 : h_b2;
    int t = threadIdx.x;
    if (t < 192) hid[t] = fmaxf(pos * w1[t] + b1[t], 0.0f);
    __syncthreads();
    if (t < 6) {
        float s = b2[t];
        for (int j = 0; j < 192; ++j) s += w2[t * 192 + j] * hid[j];
        if (is_t) tt[t * 127 + b] = s;
        else      th[t * 5 + (b - 127)] = s;
    }
}

// ---------------------------------------------------------------------------
// Kernel 1: QKV projection GEMM (fp32 compute), bf16 outputs (N,H,T,32).
// ---------------------------------------------------------------------------
__global__ __launch_bounds__(256) void qkv_kernel(
    const float* __restrict__ x, const float* __restrict__ w,
    unsigned short* __restrict__ qout, unsigned short* __restrict__ kout,
    unsigned short* __restrict__ vout)
{
    __shared__ float xs[64][33];
    __shared__ float wsh[64][33];
    int bm = blockIdx.x % 200;
    int bn = blockIdx.x / 200;
    int row0 = bm * 64, col0 = bn * 64;
    int tid = threadIdx.x;
    int ty = tid >> 4, tx = tid & 15;

    float acc[4][4];
    #pragma unroll
    for (int i = 0; i < 4; ++i)
        #pragma unroll
        for (int j = 0; j < 4; ++j) acc[i][j] = 0.0f;

    for (int k0 = 0; k0 < 192; k0 += 32) {
        __syncthreads();
        #pragma unroll
        for (int p = 0; p < 2; ++p) {
            int fid = tid + p * 256;
            int r = fid >> 3, ch = fid & 7;
            float4 a4 = *(const float4*)&x[(size_t)(row0 + r) * 192 + k0 + ch * 4];
            xs[r][ch * 4 + 0] = a4.x; xs[r][ch * 4 + 1] = a4.y;
            xs[r][ch * 4 + 2] = a4.z; xs[r][ch * 4 + 3] = a4.w;
            float4 b4 = *(const float4*)&w[(size_t)(col0 + r) * 192 + k0 + ch * 4];
            wsh[r][ch * 4 + 0] = b4.x; wsh[r][ch * 4 + 1] = b4.y;
            wsh[r][ch * 4 + 2] = b4.z; wsh[r][ch * 4 + 3] = b4.w;
        }
        __syncthreads();
        #pragma unroll
        for (int kk = 0; kk < 32; ++kk) {
            float a[4], b[4];
            #pragma unroll
            for (int i = 0; i < 4; ++i) a[i] = xs[ty * 4 + i][kk];
            #pragma unroll
            for (int j = 0; j < 4; ++j) b[j] = wsh[tx * 4 + j][kk];
            #pragma unroll
            for (int i = 0; i < 4; ++i)
                #pragma unroll
                for (int j = 0; j < 4; ++j) acc[i][j] += a[i] * b[j];
        }
    }

    int cc0 = col0 + tx * 4;
    int three = cc0 / 192;
    int rem = cc0 - three * 192;
    int h = rem >> 5, c = rem & 31;
    unsigned short* dst = (three == 0) ? qout : ((three == 1) ? kout : vout);
    #pragma unroll
    for (int i = 0; i < 4; ++i) {
        int rr = row0 + ty * 4 + i;
        int n = rr / 1600, t = rr % 1600;
        size_t idx = ((size_t)(n * 6 + h) * 1600 + t) * 32 + c;
        uint2 pk2;
        pk2.x = pack2bf(acc[i][0], acc[i][1]);
        pk2.y = pack2bf(acc[i][2], acc[i][3]);
        *(uint2*)&dst[idx] = pk2;
    }
}

// ---------------------------------------------------------------------------
// Kernel 2: fused attention, bf16 MFMA (16x16x32), swapped-QK online softmax.
// Block: 4 waves, 64 q-rows. grid = 8*6*25 = 1200 (XCD-swizzled, 150/XCD).
// Bias injected via aug-MFMA: A = [onehot(dfs) | onehot(ps)] (exact bf16),
// B = [ttl terms | hbl terms] split bf16 hi+lo for precision.
// ---------------------------------------------------------------------------
__global__ __launch_bounds__(256) void attn_kernel(
    const unsigned short* __restrict__ qw, const unsigned short* __restrict__ kw,
    const unsigned short* __restrict__ vw, const float* __restrict__ tt,
    const float* __restrict__ th, const int* __restrict__ hops,
    const float* __restrict__ alpha_p, float* __restrict__ aout)
{
    __shared__ __align__(16) unsigned short ks[64][40];   // K tile, padded
    __shared__ __align__(16) unsigned short vts[32][72];  // V transposed, padded
    __shared__ float ttl[128];
    __shared__ unsigned short fsps[1600];

    int b = blockIdx.x;
    int serial = (b & 7) * 150 + (b >> 3);   // XCD-contiguous nh chunks
    int nh = serial / 25;
    int qt = serial % 25;
    int h = nh % 6;
    int t0 = qt * 64;

    int tid = threadIdx.x;
    int lane = tid & 63, wv = tid >> 6;
    int g = lane >> 4, qi = lane & 15;

    const unsigned short* qb = qw + (size_t)nh * 1600 * 32;
    const unsigned short* kb = kw + (size_t)nh * 1600 * 32;
    const unsigned short* vb = vw + (size_t)nh * 1600 * 32;
    float* ab = aout + (size_t)nh * 1600 * 32;

    if (tid < 127) ttl[tid] = tt[h * 127 + tid];
    for (int s = tid; s < 1600; s += 256) {
        int fs = (s * 5243) >> 17;
        int ps = s - fs * 25;
        fsps[s] = (unsigned short)((fs << 5) | ps);
    }

    // per-lane q row (this wave's 16 rows; lane handles q = qi as softmax owner)
    int tq = t0 + wv * 16 + qi;
    int ft = (tq * 5243) >> 17;
    int pt = tq - ft * 25;

    bf16x8 qfrag = *(const bf16x8*)&qb[(size_t)tq * 32 + g * 8];

    // static part of B_aug: k = g*8+j ; k in [4,29) -> hbl[pt*25 + (k-4)]
    unsigned int baug_hi[4], baug_lo[4];
    #pragma unroll
    for (int jj = 0; jj < 4; ++jj) {
        int k0 = g * 8 + 2 * jj, k1 = k0 + 1;
        float v0 = 0.f, v1 = 0.f;
        if (k0 >= 4 && k0 < 29) v0 = th[h * 5 + hops[pt * 25 + (k0 - 4)]];
        if (k1 >= 4 && k1 < 29) v1 = th[h * 5 + hops[pt * 25 + (k1 - 4)]];
        unsigned short h0 = f2bf(v0), h1 = f2bf(v1);
        unsigned short l0 = f2bf(v0 - bf2f(h0)), l1 = f2bf(v1 - bf2f(h1));
        baug_hi[jj] = (unsigned)h0 | ((unsigned)h1 << 16);
        baug_lo[jj] = (unsigned)l0 | ((unsigned)l1 << 16);
    }

    float m = -1e30f, l = 0.f;
    f32x4 O0 = {0.f, 0.f, 0.f, 0.f}, O1 = {0.f, 0.f, 0.f, 0.f};

    for (int s0 = 0; s0 < 1600; s0 += 64) {
        __syncthreads();
        {   // stage K (row-major padded) and V (transposed padded)
            int row = tid >> 2, c8 = (tid & 3) * 8;
            *(uint4*)&ks[row][c8] = *(const uint4*)&kb[(size_t)(s0 + row) * 32 + c8];
            union { uint4 u; unsigned short s[8]; } vv;
            vv.u = *(const uint4*)&vb[(size_t)(s0 + row) * 32 + c8];
            #pragma unroll
            for (int j = 0; j < 8; ++j) vts[c8 + j][row] = vv.s[j];
        }
        __syncthreads();

        int fs0 = fsps[s0] >> 5;

        // dynamic ttl slots (k=0..3) of B_aug, only g==0 lanes
        unsigned int bh0 = baug_hi[0], bh1 = baug_hi[1];
        unsigned int bl0 = baug_lo[0], bl1 = baug_lo[1];
        if (g == 0) {
            int base = ft - fs0 + 63;
            float tv0 = ttl[max(base, 0)];
            float tv1 = ttl[max(base - 1, 0)];
            float tv2 = ttl[max(base - 2, 0)];
            float tv3 = ttl[max(base - 3, 0)];
            unsigned short h0 = f2bf(tv0), h1 = f2bf(tv1), h2 = f2bf(tv2), h3 = f2bf(tv3);
            bh0 = (unsigned)h0 | ((unsigned)h1 << 16);
            bh1 = (unsigned)h2 | ((unsigned)h3 << 16);
            unsigned short l0s = f2bf(tv0 - bf2f(h0)), l1s = f2bf(tv1 - bf2f(h1));
            unsigned short l2s = f2bf(tv2 - bf2f(h2)), l3s = f2bf(tv3 - bf2f(h3));
            bl0 = (unsigned)l0s | ((unsigned)l1s << 16);
            bl1 = (unsigned)l2s | ((unsigned)l3s << 16);
        }
        uint4v bhiu = {bh0, bh1, baug_hi[2], baug_hi[3]};
        uint4v blou = {bl0, bl1, baug_lo[2], baug_lo[3]};
        bf16x8 bhif = __builtin_bit_cast(bf16x8, bhiu);
        bf16x8 blof = __builtin_bit_cast(bf16x8, blou);

        f32x4 sfr[4];
        #pragma unroll
        for (int sb = 0; sb < 4; ++sb) {
            int s = s0 + sb * 16 + qi;
            unsigned int uu = fsps[s];
            int dfs = (int)(uu >> 5) - fs0;
            int ps = (int)(uu & 31u);
            unsigned int a[4];
            #pragma unroll
            for (int jj = 0; jj < 4; ++jj) {
                int k0 = g * 8 + 2 * jj, k1 = k0 + 1;
                bool c0 = (k0 < 4) ? (dfs == k0) : (ps == k0 - 4);
                bool c1 = (k1 < 4) ? (dfs == k1) : (ps == k1 - 4);
                a[jj] = (c0 ? 0x3F80u : 0u) | (c1 ? 0x3F800000u : 0u);
            }
            uint4v au = {a[0], a[1], a[2], a[3]};
            bf16x8 af = __builtin_bit_cast(bf16x8, au);
            bf16x8 kf = *(const bf16x8*)&ks[sb * 16 + qi][g * 8];
            f32x4 cz = {0.f, 0.f, 0.f, 0.f};
            f32x4 cb = __builtin_amdgcn_mfma_f32_16x16x32_bf16(af, blof, cz, 0, 0, 0);
            cb = __builtin_amdgcn_mfma_f32_16x16x32_bf16(af, bhif, cb, 0, 0, 0);
            sfr[sb] = __builtin_amdgcn_mfma_f32_16x16x32_bf16(kf, qfrag, cb, 0, 0, 0);
        }

        // online softmax over this 64-s tile (lane owns q = qi; 16 vals/lane)
        float mt = -1e30f;
        #pragma unroll
        for (int sb = 0; sb < 4; ++sb)
            #pragma unroll
            for (int r = 0; r < 4; ++r) mt = fmaxf(mt, sfr[sb][r]);
        mt *= SCALE_;
        mt = fmaxf(mt, __shfl_xor(mt, 16, 64));
        mt = fmaxf(mt, __shfl_xor(mt, 32, 64));
        float mnew = fmaxf(m, mt);
        float sc = __expf(m - mnew);
        m = mnew;
        l *= sc;
        #pragma unroll
        for (int r = 0; r < 4; ++r) {
            float scr = __uint_as_float(
                __builtin_amdgcn_ds_bpermute((4 * g + r) << 2, __float_as_uint(sc)));
            O0[r] *= scr; O1[r] *= scr;
        }
        float p[4][4];
        float lt = 0.f;
        #pragma unroll
        for (int sb = 0; sb < 4; ++sb)
            #pragma unroll
            for (int r = 0; r < 4; ++r) {
                float pv = __expf(sfr[sb][r] * SCALE_ - mnew);
                p[sb][r] = pv;
                lt += pv;
            }
        lt += __shfl_xor(lt, 16, 64);
        lt += __shfl_xor(lt, 32, 64);
        l += lt;

        // pack P to bf16 pairs, redistribute to A-frag layout via bpermute
        unsigned int pkk[4][2];
        #pragma unroll
        for (int sb = 0; sb < 4; ++sb) {
            pkk[sb][0] = pack2bf(p[sb][0], p[sb][1]);
            pkk[sb][1] = pack2bf(p[sb][2], p[sb][3]);
        }
        #pragma unroll
        for (int c = 0; c < 2; ++c) {
            unsigned int pa[4];
            #pragma unroll
            for (int jj = 0; jj < 4; ++jj) {
                int srcl = (((2 * g + (jj >> 1)) & 3) * 16 + qi) << 2;
                unsigned int vA = (unsigned)__builtin_amdgcn_ds_bpermute(srcl, (int)pkk[2 * c][jj & 1]);
                unsigned int vB = (unsigned)__builtin_amdgcn_ds_bpermute(srcl, (int)pkk[2 * c + 1][jj & 1]);
                pa[jj] = (g < 2) ? vA : vB;
            }
            uint4v pau = {pa[0], pa[1], pa[2], pa[3]};
            bf16x8 paf = __builtin_bit_cast(bf16x8, pau);
            bf16x8 v0f = *(const bf16x8*)&vts[qi][c * 32 + g * 8];
            bf16x8 v1f = *(const bf16x8*)&vts[16 + qi][c * 32 + g * 8];
            O0 = __builtin_amdgcn_mfma_f32_16x16x32_bf16(paf, v0f, O0, 0, 0, 0);
            O1 = __builtin_amdgcn_mfma_f32_16x16x32_bf16(paf, v1f, O1, 0, 0, 0);
        }
    }

    float alpha = alpha_p[0];
    float winv = alpha / l;
    int trow = t0 + wv * 16;
    #pragma unroll
    for (int r = 0; r < 4; ++r) {
        float wr = __uint_as_float(
            __builtin_amdgcn_ds_bpermute((4 * g + r) << 2, __float_as_uint(winv)));
        ab[(size_t)(trow + 4 * g + r) * 32 + qi] = O0[r] * wr;
        ab[(size_t)(trow + 4 * g + r) * 32 + 16 + qi] = O1[r] * wr;
    }
}

// ---------------------------------------------------------------------------
// Kernel 3: fuse relational (outer) term and final projection (v is bf16).
// ---------------------------------------------------------------------------
__global__ __launch_bounds__(256) void proj_kernel(
    const float* __restrict__ ao, const unsigned short* __restrict__ vw,
    const float* __restrict__ outer, const float* __restrict__ pw,
    const float* __restrict__ pb, float* __restrict__ out)
{
    __shared__ float comb[16][193];
    __shared__ float wsh[192][33];
    int blk = blockIdx.x;
    int n = blk / 100;
    int t0 = (blk % 100) * 16;
    int tid = threadIdx.x;

    for (int e = tid; e < 16 * 192; e += 256) {
        int r = e / 192;
        int j = e - r * 192;
        int t = t0 + r;
        int hh = j >> 5, c = j & 31;
        int ftt = t / 25;
        int ptt = t - ftt * 25;
        const unsigned short* vrow = vw + ((size_t)(n * 6 + hh) * 1600 + ftt * 25) * 32 + c;
        const float* orow = outer + hh * 625 + ptt * 25;
        float s = ao[((size_t)(n * 6 + hh) * 1600 + t) * 32 + c];
        #pragma unroll
        for (int q = 0; q < 25; ++q) s += orow[q] * bf2f(vrow[q * 32]);
        comb[r][j] = s;
    }

    int ty = tid >> 4, tx = tid & 15;
    float accp[12];
    #pragma unroll
    for (int jj = 0; jj < 12; ++jj) accp[jj] = 0.0f;

    for (int k0 = 0; k0 < 192; k0 += 32) {
        __syncthreads();
        #pragma unroll
        for (int p = 0; p < 6; ++p) {
            int fid = tid + p * 256;
            int j = fid >> 3, ch = fid & 7;
            float4 w4 = *(const float4*)&pw[(size_t)j * 192 + k0 + ch * 4];
            wsh[j][ch * 4 + 0] = w4.x; wsh[j][ch * 4 + 1] = w4.y;
            wsh[j][ch * 4 + 2] = w4.z; wsh[j][ch * 4 + 3] = w4.w;
        }
        __syncthreads();
        #pragma unroll
        for (int kk = 0; kk < 32; ++kk) {
            float a = comb[ty][k0 + kk];
            #pragma unroll
            for (int jj = 0; jj < 12; ++jj) accp[jj] += a * wsh[tx + 16 * jj][kk];
        }
    }

    #pragma unroll
    for (int jj = 0; jj < 12; ++jj) {
        int j = tx + 16 * jj;
        out[(size_t)(n * 1600 + t0 + ty) * 192 + j] = accp[jj] + pb[j];
    }
}

// ---------------------------------------------------------------------------
extern "C" void kernel_launch(void* const* d_in, const int* in_sizes, int n_in,
                              void* d_out, int out_size, void* d_ws, size_t ws_size,
                              hipStream_t stream)
{
    const float* x      = (const float*)d_in[0];
    const float* qkv_w  = (const float*)d_in[1];
    const float* proj_w = (const float*)d_in[2];
    const float* proj_b = (const float*)d_in[3];
    const float* t_w1   = (const float*)d_in[4];
    const float* t_b1   = (const float*)d_in[5];
    const float* t_w2   = (const float*)d_in[6];
    const float* t_b2   = (const float*)d_in[7];
    const float* h_w1   = (const float*)d_in[8];
    const float* h_b1   = (const float*)d_in[9];
    const float* h_w2   = (const float*)d_in[10];
    const float* h_b2   = (const float*)d_in[11];
    const float* outer  = (const float*)d_in[12];
    const float* alpha  = (const float*)d_in[13];
    const int*   hops   = (const int*)d_in[14];
    float* out = (float*)d_out;

    char* w8 = (char*)d_ws;
    float* tt = (float*)w8;                      // 762 floats
    float* th = tt + 762;                        // 30 floats
    unsigned short* qb = (unsigned short*)(w8 + 4096);
    unsigned short* kb = qb + 2457600;
    unsigned short* vb = kb + 2457600;
    float* ab = (float*)(w8 + 4096 + 3 * 4915200);

    bias_tables_kernel<<<132, 192, 0, stream>>>(t_w1, t_b1, t_w2, t_b2,
                                                h_w1, h_b1, h_w2, h_b2, tt, th);
    qkv_kernel<<<1800, 256, 0, stream>>>(x, qkv_w, qb, kb, vb);
    attn_kernel<<<1200, 256, 0, stream>>>(qb, kb, vb, tt, th, hops, alpha, ab);
    proj_kernel<<<800, 256, 0, stream>>>(ab, vb, outer, proj_w, proj_b, out);
}

// Round 5
// 152.634 us; speedup vs baseline: 5.7228x; 2.1115x over previous
//
#include <hip/hip_runtime.h>
#include <math.h>

#define N_ 8
#define F_ 64
#define P_ 25
#define H_ 6
#define D_ 192
#define HD_ 32
#define T_ 1600
#define SCALE_ 0.17677669529663687f

typedef short bf16x8 __attribute__((ext_vector_type(8)));
typedef float f32x4 __attribute__((ext_vector_type(4)));
typedef unsigned int uint4v __attribute__((ext_vector_type(4)));

__device__ __forceinline__ unsigned short f2bf(float f) {
    unsigned int u = __float_as_uint(f);
    u += 0x7fffu + ((u >> 16) & 1u);
    return (unsigned short)(u >> 16);
}
__device__ __forceinline__ float bf2f(unsigned short s) {
    return __uint_as_float(((unsigned int)s) << 16);
}
__device__ __forceinline__ unsigned int pack2bf(float lo, float hi) {
    return (unsigned int)f2bf(lo) | ((unsigned int)f2bf(hi) << 16);
}

// ---------------------------------------------------------------------------
// Kernel 0: evaluate the two bias MLPs into workspace tables.
// ---------------------------------------------------------------------------
__global__ void bias_tables_kernel(
    const float* __restrict__ t_w1, const float* __restrict__ t_b1,
    const float* __restrict__ t_w2, const float* __restrict__ t_b2,
    const float* __restrict__ h_w1, const float* __restrict__ h_b1,
    const float* __restrict__ h_w2, const float* __restrict__ h_b2,
    float* __restrict__ tt, float* __restrict__ th)
{
    __shared__ float hid[192];
    int b = blockIdx.x;
    bool is_t = (b < 127);
    float pos = is_t ? (float)(b - 63) : (float)(b - 127);
    const float* w1 = is_t ? t_w1 : h_w1;
    const float* b1 = is_t ? t_b1 : h_b1;
    const float* w2 = is_t ? t_w2 : h_w2;
    const float* b2 = is_t ? t_b2 : h_b2;
    int t = threadIdx.x;
    if (t < 192) hid[t] = fmaxf(pos * w1[t] + b1[t], 0.0f);
    __syncthreads();
    if (t < 6) {
        float s = b2[t];
        for (int j = 0; j < 192; ++j) s += w2[t * 192 + j] * hid[j];
        if (is_t) tt[t * 127 + b] = s;
        else      th[t * 5 + (b - 127)] = s;
    }
}

// ---------------------------------------------------------------------------
// Kernel 1: QKV projection, bf16 MFMA GEMM. M=12800, N=576, K=192.
// 64x64 tiles, 4 waves x (16 rows x 64 cols). A (x) staged full-K as bf16,
// B (qkv_w) staged per 64-K chunk as bf16. Scatter epilogue into (N,H,T,32).
// grid: 200 * 9 = 1800 blocks
// ---------------------------------------------------------------------------
__global__ __launch_bounds__(256) void qkv_gemm_kernel(
    const float* __restrict__ x, const float* __restrict__ w,
    unsigned short* __restrict__ qout, unsigned short* __restrict__ kout,
    unsigned short* __restrict__ vout)
{
    __shared__ __align__(16) unsigned short alds[64][200];
    __shared__ __align__(16) unsigned short blds[64][72];

    int b = blockIdx.x;
    int bm = b % 200, bn = b / 200;
    int row0 = bm * 64, col0 = bn * 64;
    int tid = threadIdx.x, lane = tid & 63, wv = tid >> 6;
    int g = lane >> 4, qi = lane & 15;

    // stage A: x[row0..+64][0..192] fp32 -> bf16
    #pragma unroll
    for (int p = 0; p < 12; ++p) {
        int fid = tid + p * 256;          // 3072 float4 = 64 rows * 48
        int r = fid / 48, c4 = (fid % 48) * 4;
        float4 a4 = *(const float4*)&x[(size_t)(row0 + r) * 192 + c4];
        uint2 pk;
        pk.x = pack2bf(a4.x, a4.y);
        pk.y = pack2bf(a4.z, a4.w);
        *(uint2*)&alds[r][c4] = pk;
    }

    f32x4 acc[4];
    #pragma unroll
    for (int nt = 0; nt < 4; ++nt) acc[nt] = (f32x4){0.f, 0.f, 0.f, 0.f};

    for (int k0 = 0; k0 < 192; k0 += 64) {
        __syncthreads();
        #pragma unroll
        for (int p = 0; p < 4; ++p) {
            int fid = tid + p * 256;      // 1024 float4 = 64 cols * 16
            int j = fid >> 4, k4 = (fid & 15) * 4;
            float4 w4 = *(const float4*)&w[(size_t)(col0 + j) * 192 + k0 + k4];
            uint2 pk;
            pk.x = pack2bf(w4.x, w4.y);
            pk.y = pack2bf(w4.z, w4.w);
            *(uint2*)&blds[j][k4] = pk;
        }
        __syncthreads();
        #pragma unroll
        for (int ks = 0; ks < 2; ++ks) {
            bf16x8 af = *(const bf16x8*)&alds[wv * 16 + qi][k0 + ks * 32 + g * 8];
            #pragma unroll
            for (int nt = 0; nt < 4; ++nt) {
                bf16x8 bf = *(const bf16x8*)&blds[nt * 16 + qi][ks * 32 + g * 8];
                acc[nt] = __builtin_amdgcn_mfma_f32_16x16x32_bf16(af, bf, acc[nt], 0, 0, 0);
            }
        }
    }

    // scatter epilogue: col -> (three, h, c); row -> (n, t)
    #pragma unroll
    for (int nt = 0; nt < 4; ++nt) {
        int col = col0 + nt * 16 + qi;
        int three = col / 192;
        int rem = col - three * 192;
        int h = rem >> 5, c = rem & 31;
        unsigned short* dst = (three == 0) ? qout : ((three == 1) ? kout : vout);
        #pragma unroll
        for (int r = 0; r < 4; ++r) {
            int row = row0 + wv * 16 + 4 * g + r;
            int n = row / 1600, t = row - n * 1600;
            dst[((size_t)(n * 6 + h) * 1600 + t) * 32 + c] = f2bf(acc[nt][r]);
        }
    }
}

// ---------------------------------------------------------------------------
// Kernel 2: fused attention, bf16 MFMA (16x16x32), swapped-QK online softmax.
// (unchanged from round 4 — passed with absmax 0.0078)
// ---------------------------------------------------------------------------
__global__ __launch_bounds__(256) void attn_kernel(
    const unsigned short* __restrict__ qw, const unsigned short* __restrict__ kw,
    const unsigned short* __restrict__ vw, const float* __restrict__ tt,
    const float* __restrict__ th, const int* __restrict__ hops,
    const float* __restrict__ alpha_p, float* __restrict__ aout)
{
    __shared__ __align__(16) unsigned short ks[64][40];   // K tile, padded
    __shared__ __align__(16) unsigned short vts[32][72];  // V transposed, padded
    __shared__ float ttl[128];
    __shared__ unsigned short fsps[1600];

    int b = blockIdx.x;
    int serial = (b & 7) * 150 + (b >> 3);   // XCD-contiguous nh chunks
    int nh = serial / 25;
    int qt = serial % 25;
    int h = nh % 6;
    int t0 = qt * 64;

    int tid = threadIdx.x;
    int lane = tid & 63, wv = tid >> 6;
    int g = lane >> 4, qi = lane & 15;

    const unsigned short* qb = qw + (size_t)nh * 1600 * 32;
    const unsigned short* kb = kw + (size_t)nh * 1600 * 32;
    const unsigned short* vb = vw + (size_t)nh * 1600 * 32;
    float* ab = aout + (size_t)nh * 1600 * 32;

    if (tid < 127) ttl[tid] = tt[h * 127 + tid];
    for (int s = tid; s < 1600; s += 256) {
        int fs = (s * 5243) >> 17;
        int ps = s - fs * 25;
        fsps[s] = (unsigned short)((fs << 5) | ps);
    }

    int tq = t0 + wv * 16 + qi;
    int ft = (tq * 5243) >> 17;
    int pt = tq - ft * 25;

    bf16x8 qfrag = *(const bf16x8*)&qb[(size_t)tq * 32 + g * 8];

    unsigned int baug_hi[4], baug_lo[4];
    #pragma unroll
    for (int jj = 0; jj < 4; ++jj) {
        int k0 = g * 8 + 2 * jj, k1 = k0 + 1;
        float v0 = 0.f, v1 = 0.f;
        if (k0 >= 4 && k0 < 29) v0 = th[h * 5 + hops[pt * 25 + (k0 - 4)]];
        if (k1 >= 4 && k1 < 29) v1 = th[h * 5 + hops[pt * 25 + (k1 - 4)]];
        unsigned short h0 = f2bf(v0), h1 = f2bf(v1);
        unsigned short l0 = f2bf(v0 - bf2f(h0)), l1 = f2bf(v1 - bf2f(h1));
        baug_hi[jj] = (unsigned)h0 | ((unsigned)h1 << 16);
        baug_lo[jj] = (unsigned)l0 | ((unsigned)l1 << 16);
    }

    float m = -1e30f, l = 0.f;
    f32x4 O0 = {0.f, 0.f, 0.f, 0.f}, O1 = {0.f, 0.f, 0.f, 0.f};

    for (int s0 = 0; s0 < 1600; s0 += 64) {
        __syncthreads();
        {
            int row = tid >> 2, c8 = (tid & 3) * 8;
            *(uint4*)&ks[row][c8] = *(const uint4*)&kb[(size_t)(s0 + row) * 32 + c8];
            union { uint4 u; unsigned short s[8]; } vv;
            vv.u = *(const uint4*)&vb[(size_t)(s0 + row) * 32 + c8];
            #pragma unroll
            for (int j = 0; j < 8; ++j) vts[c8 + j][row] = vv.s[j];
        }
        __syncthreads();

        int fs0 = fsps[s0] >> 5;

        unsigned int bh0 = baug_hi[0], bh1 = baug_hi[1];
        unsigned int bl0 = baug_lo[0], bl1 = baug_lo[1];
        if (g == 0) {
            int base = ft - fs0 + 63;
            float tv0 = ttl[max(base, 0)];
            float tv1 = ttl[max(base - 1, 0)];
            float tv2 = ttl[max(base - 2, 0)];
            float tv3 = ttl[max(base - 3, 0)];
            unsigned short h0 = f2bf(tv0), h1 = f2bf(tv1), h2 = f2bf(tv2), h3 = f2bf(tv3);
            bh0 = (unsigned)h0 | ((unsigned)h1 << 16);
            bh1 = (unsigned)h2 | ((unsigned)h3 << 16);
            unsigned short l0s = f2bf(tv0 - bf2f(h0)), l1s = f2bf(tv1 - bf2f(h1));
            unsigned short l2s = f2bf(tv2 - bf2f(h2)), l3s = f2bf(tv3 - bf2f(h3));
            bl0 = (unsigned)l0s | ((unsigned)l1s << 16);
            bl1 = (unsigned)l2s | ((unsigned)l3s << 16);
        }
        uint4v bhiu = {bh0, bh1, baug_hi[2], baug_hi[3]};
        uint4v blou = {bl0, bl1, baug_lo[2], baug_lo[3]};
        bf16x8 bhif = __builtin_bit_cast(bf16x8, bhiu);
        bf16x8 blof = __builtin_bit_cast(bf16x8, blou);

        f32x4 sfr[4];
        #pragma unroll
        for (int sb = 0; sb < 4; ++sb) {
            int s = s0 + sb * 16 + qi;
            unsigned int uu = fsps[s];
            int dfs = (int)(uu >> 5) - fs0;
            int ps = (int)(uu & 31u);
            unsigned int a[4];
            #pragma unroll
            for (int jj = 0; jj < 4; ++jj) {
                int k0 = g * 8 + 2 * jj, k1 = k0 + 1;
                bool c0 = (k0 < 4) ? (dfs == k0) : (ps == k0 - 4);
                bool c1 = (k1 < 4) ? (dfs == k1) : (ps == k1 - 4);
                a[jj] = (c0 ? 0x3F80u : 0u) | (c1 ? 0x3F800000u : 0u);
            }
            uint4v au = {a[0], a[1], a[2], a[3]};
            bf16x8 af = __builtin_bit_cast(bf16x8, au);
            bf16x8 kf = *(const bf16x8*)&ks[sb * 16 + qi][g * 8];
            f32x4 cz = {0.f, 0.f, 0.f, 0.f};
            f32x4 cb = __builtin_amdgcn_mfma_f32_16x16x32_bf16(af, blof, cz, 0, 0, 0);
            cb = __builtin_amdgcn_mfma_f32_16x16x32_bf16(af, bhif, cb, 0, 0, 0);
            sfr[sb] = __builtin_amdgcn_mfma_f32_16x16x32_bf16(kf, qfrag, cb, 0, 0, 0);
        }

        float mt = -1e30f;
        #pragma unroll
        for (int sb = 0; sb < 4; ++sb)
            #pragma unroll
            for (int r = 0; r < 4; ++r) mt = fmaxf(mt, sfr[sb][r]);
        mt *= SCALE_;
        mt = fmaxf(mt, __shfl_xor(mt, 16, 64));
        mt = fmaxf(mt, __shfl_xor(mt, 32, 64));
        float mnew = fmaxf(m, mt);
        float sc = __expf(m - mnew);
        m = mnew;
        l *= sc;
        #pragma unroll
        for (int r = 0; r < 4; ++r) {
            float scr = __uint_as_float(
                __builtin_amdgcn_ds_bpermute((4 * g + r) << 2, __float_as_uint(sc)));
            O0[r] *= scr; O1[r] *= scr;
        }
        float p[4][4];
        float lt = 0.f;
        #pragma unroll
        for (int sb = 0; sb < 4; ++sb)
            #pragma unroll
            for (int r = 0; r < 4; ++r) {
                float pv = __expf(sfr[sb][r] * SCALE_ - mnew);
                p[sb][r] = pv;
                lt += pv;
            }
        lt += __shfl_xor(lt, 16, 64);
        lt += __shfl_xor(lt, 32, 64);
        l += lt;

        unsigned int pkk[4][2];
        #pragma unroll
        for (int sb = 0; sb < 4; ++sb) {
            pkk[sb][0] = pack2bf(p[sb][0], p[sb][1]);
            pkk[sb][1] = pack2bf(p[sb][2], p[sb][3]);
        }
        #pragma unroll
        for (int c = 0; c < 2; ++c) {
            unsigned int pa[4];
            #pragma unroll
            for (int jj = 0; jj < 4; ++jj) {
                int srcl = (((2 * g + (jj >> 1)) & 3) * 16 + qi) << 2;
                unsigned int vA = (unsigned)__builtin_amdgcn_ds_bpermute(srcl, (int)pkk[2 * c][jj & 1]);
                unsigned int vB = (unsigned)__builtin_amdgcn_ds_bpermute(srcl, (int)pkk[2 * c + 1][jj & 1]);
                pa[jj] = (g < 2) ? vA : vB;
            }
            uint4v pau = {pa[0], pa[1], pa[2], pa[3]};
            bf16x8 paf = __builtin_bit_cast(bf16x8, pau);
            bf16x8 v0f = *(const bf16x8*)&vts[qi][c * 32 + g * 8];
            bf16x8 v1f = *(const bf16x8*)&vts[16 + qi][c * 32 + g * 8];
            O0 = __builtin_amdgcn_mfma_f32_16x16x32_bf16(paf, v0f, O0, 0, 0, 0);
            O1 = __builtin_amdgcn_mfma_f32_16x16x32_bf16(paf, v1f, O1, 0, 0, 0);
        }
    }

    float alpha = alpha_p[0];
    float winv = alpha / l;
    int trow = t0 + wv * 16;
    #pragma unroll
    for (int r = 0; r < 4; ++r) {
        float wr = __uint_as_float(
            __builtin_amdgcn_ds_bpermute((4 * g + r) << 2, __float_as_uint(winv)));
        ab[(size_t)(trow + 4 * g + r) * 32 + qi] = O0[r] * wr;
        ab[(size_t)(trow + 4 * g + r) * 32 + 16 + qi] = O1[r] * wr;
    }
}

// ---------------------------------------------------------------------------
// Kernel 3a: relational term. comb[n*1600+t][h*32+c] =
//   ab[n,h,t,c] + sum_q outer[h,pt,q] * v[n,h,ft*25+q,c]   (bf16 out)
// block per (n,h,f): grid 8*6*64 = 3072
// ---------------------------------------------------------------------------
__global__ __launch_bounds__(256) void rel_kernel(
    const float* __restrict__ ab, const unsigned short* __restrict__ vw,
    const float* __restrict__ outer, unsigned short* __restrict__ comb)
{
    __shared__ float olds[25][26];
    __shared__ unsigned short vlds[25][32];
    int b = blockIdx.x;
    int n = b / 384;
    int h = (b / 64) % 6;
    int f = b & 63;
    int tid = threadIdx.x;

    for (int e = tid; e < 625; e += 256) olds[e / 25][e % 25] = outer[h * 625 + e];
    size_t vbase = ((size_t)(n * 6 + h) * 1600 + f * 25) * 32;
    for (int e = tid; e < 400; e += 256)
        ((unsigned int*)&vlds[0][0])[e] = *(const unsigned int*)&vw[vbase + e * 2];
    __syncthreads();

    size_t abase = vbase;  // same (n,h,t,c) layout for ab
    size_t cbase = ((size_t)n * 1600 + f * 25) * 192 + h * 32;
    for (int e = tid; e < 800; e += 256) {
        int p = e >> 5, c = e & 31;
        float s = ab[abase + e];
        #pragma unroll
        for (int q = 0; q < 25; ++q) s += olds[p][q] * bf2f(vlds[q][c]);
        comb[cbase + (size_t)p * 192 + c] = f2bf(s);
    }
}

// ---------------------------------------------------------------------------
// Kernel 3b: final projection, bf16 MFMA GEMM. out[12800][192] =
//   comb[12800][192] @ proj_w[192][192]^T + proj_b.
// 64x64 tiles, grid 200*3 = 600.
// ---------------------------------------------------------------------------
__global__ __launch_bounds__(256) void proj_gemm_kernel(
    const unsigned short* __restrict__ comb, const float* __restrict__ pw,
    const float* __restrict__ pb, float* __restrict__ out)
{
    __shared__ __align__(16) unsigned short alds[64][200];
    __shared__ __align__(16) unsigned short blds[64][72];

    int b = blockIdx.x;
    int bm = b % 200, bn = b / 200;
    int row0 = bm * 64, col0 = bn * 64;
    int tid = threadIdx.x, lane = tid & 63, wv = tid >> 6;
    int g = lane >> 4, qi = lane & 15;

    // stage A (already bf16, coalesced 16B)
    #pragma unroll
    for (int p = 0; p < 6; ++p) {
        int fid = tid + p * 256;          // 1536 = 64 rows * 24 bf16x8
        int r = fid / 24, c8 = (fid % 24) * 8;
        *(uint4*)&alds[r][c8] = *(const uint4*)&comb[(size_t)(row0 + r) * 192 + c8];
    }

    f32x4 acc[4];
    #pragma unroll
    for (int nt = 0; nt < 4; ++nt) acc[nt] = (f32x4){0.f, 0.f, 0.f, 0.f};

    for (int k0 = 0; k0 < 192; k0 += 64) {
        __syncthreads();
        #pragma unroll
        for (int p = 0; p < 4; ++p) {
            int fid = tid + p * 256;      // 1024 float4 = 64 cols * 16
            int j = fid >> 4, k4 = (fid & 15) * 4;
            float4 w4 = *(const float4*)&pw[(size_t)(col0 + j) * 192 + k0 + k4];
            uint2 pk;
            pk.x = pack2bf(w4.x, w4.y);
            pk.y = pack2bf(w4.z, w4.w);
            *(uint2*)&blds[j][k4] = pk;
        }
        __syncthreads();
        #pragma unroll
        for (int ks = 0; ks < 2; ++ks) {
            bf16x8 af = *(const bf16x8*)&alds[wv * 16 + qi][k0 + ks * 32 + g * 8];
            #pragma unroll
            for (int nt = 0; nt < 4; ++nt) {
                bf16x8 bf = *(const bf16x8*)&blds[nt * 16 + qi][ks * 32 + g * 8];
                acc[nt] = __builtin_amdgcn_mfma_f32_16x16x32_bf16(af, bf, acc[nt], 0, 0, 0);
            }
        }
    }

    #pragma unroll
    for (int nt = 0; nt < 4; ++nt) {
        int col = col0 + nt * 16 + qi;
        float bias = pb[col];
        #pragma unroll
        for (int r = 0; r < 4; ++r) {
            int row = row0 + wv * 16 + 4 * g + r;
            out[(size_t)row * 192 + col] = acc[nt][r] + bias;
        }
    }
}

// ---------------------------------------------------------------------------
extern "C" void kernel_launch(void* const* d_in, const int* in_sizes, int n_in,
                              void* d_out, int out_size, void* d_ws, size_t ws_size,
                              hipStream_t stream)
{
    const float* x      = (const float*)d_in[0];
    const float* qkv_w  = (const float*)d_in[1];
    const float* proj_w = (const float*)d_in[2];
    const float* proj_b = (const float*)d_in[3];
    const float* t_w1   = (const float*)d_in[4];
    const float* t_b1   = (const float*)d_in[5];
    const float* t_w2   = (const float*)d_in[6];
    const float* t_b2   = (const float*)d_in[7];
    const float* h_w1   = (const float*)d_in[8];
    const float* h_b1   = (const float*)d_in[9];
    const float* h_w2   = (const float*)d_in[10];
    const float* h_b2   = (const float*)d_in[11];
    const float* outer  = (const float*)d_in[12];
    const float* alpha  = (const float*)d_in[13];
    const int*   hops   = (const int*)d_in[14];
    float* out = (float*)d_out;

    char* w8 = (char*)d_ws;
    float* tt = (float*)w8;                      // 762 floats
    float* th = tt + 762;                        // 30 floats
    unsigned short* qb = (unsigned short*)(w8 + 4096);
    unsigned short* kb = qb + 2457600;
    unsigned short* vb = kb + 2457600;
    float* ab = (float*)(w8 + 4096 + 3 * 4915200);
    unsigned short* comb = qb;                   // reuse q buffer (dead after attn)

    bias_tables_kernel<<<132, 192, 0, stream>>>(t_w1, t_b1, t_w2, t_b2,
                                                h_w1, h_b1, h_w2, h_b2, tt, th);
    qkv_gemm_kernel<<<1800, 256, 0, stream>>>(x, qkv_w, qb, kb, vb);
    attn_kernel<<<1200, 256, 0, stream>>>(qb, kb, vb, tt, th, hops, alpha, ab);
    rel_kernel<<<3072, 256, 0, stream>>>(ab, vb, outer, comb);
    proj_gemm_kernel<<<600, 256, 0, stream>>>(comb, proj_w, proj_b, out);
}

// Round 8
// 150.687 us; speedup vs baseline: 5.7967x; 1.0129x over previous
//
#include <hip/hip_runtime.h>
#include <math.h>

#define N_ 8
#define F_ 64
#define P_ 25
#define H_ 6
#define D_ 192
#define HD_ 32
#define T_ 1600
#define SCALE_ 0.17677669529663687f
#define SC2F 0.25503486f   // SCALE * log2(e)

typedef short bf16x8 __attribute__((ext_vector_type(8)));
typedef float f32x4 __attribute__((ext_vector_type(4)));
typedef unsigned int uint4v __attribute__((ext_vector_type(4)));

__device__ __forceinline__ unsigned short f2bf(float f) {
    unsigned int u = __float_as_uint(f);
    u += 0x7fffu + ((u >> 16) & 1u);
    return (unsigned short)(u >> 16);
}
__device__ __forceinline__ float bf2f(unsigned short s) {
    return __uint_as_float(((unsigned int)s) << 16);
}
__device__ __forceinline__ unsigned int pack2bf(float lo, float hi) {
    return (unsigned int)f2bf(lo) | ((unsigned int)f2bf(hi) << 16);
}
__device__ __forceinline__ unsigned int cvt_pk_bf16(float lo, float hi) {
    unsigned int r;
    asm("v_cvt_pk_bf16_f32 %0, %1, %2" : "=v"(r) : "v"(lo), "v"(hi));
    return r;
}

// ---------------------------------------------------------------------------
// Kernel 0: evaluate the two bias MLPs into workspace tables.
// ---------------------------------------------------------------------------
__global__ void bias_tables_kernel(
    const float* __restrict__ t_w1, const float* __restrict__ t_b1,
    const float* __restrict__ t_w2, const float* __restrict__ t_b2,
    const float* __restrict__ h_w1, const float* __restrict__ h_b1,
    const float* __restrict__ h_w2, const float* __restrict__ h_b2,
    float* __restrict__ tt, float* __restrict__ th)
{
    __shared__ float hid[192];
    int b = blockIdx.x;
    bool is_t = (b < 127);
    float pos = is_t ? (float)(b - 63) : (float)(b - 127);
    const float* w1 = is_t ? t_w1 : h_w1;
    const float* b1 = is_t ? t_b1 : h_b1;
    const float* w2 = is_t ? t_w2 : h_w2;
    const float* b2 = is_t ? t_b2 : h_b2;
    int t = threadIdx.x;
    if (t < 192) hid[t] = fmaxf(pos * w1[t] + b1[t], 0.0f);
    __syncthreads();
    if (t < 6) {
        float s = b2[t];
        for (int j = 0; j < 192; ++j) s += w2[t * 192 + j] * hid[j];
        if (is_t) tt[t * 127 + b] = s;
        else      th[t * 5 + (b - 127)] = s;
    }
}

// ---------------------------------------------------------------------------
// Kernel 1: QKV projection, bf16 MFMA GEMM. (unchanged)
// ---------------------------------------------------------------------------
__global__ __launch_bounds__(256) void qkv_gemm_kernel(
    const float* __restrict__ x, const float* __restrict__ w,
    unsigned short* __restrict__ qout, unsigned short* __restrict__ kout,
    unsigned short* __restrict__ vout)
{
    __shared__ __align__(16) unsigned short alds[64][200];
    __shared__ __align__(16) unsigned short blds[64][72];

    int b = blockIdx.x;
    int bm = b % 200, bn = b / 200;
    int row0 = bm * 64, col0 = bn * 64;
    int tid = threadIdx.x, lane = tid & 63, wv = tid >> 6;
    int g = lane >> 4, qi = lane & 15;

    #pragma unroll
    for (int p = 0; p < 12; ++p) {
        int fid = tid + p * 256;
        int r = fid / 48, c4 = (fid % 48) * 4;
        float4 a4 = *(const float4*)&x[(size_t)(row0 + r) * 192 + c4];
        uint2 pk;
        pk.x = pack2bf(a4.x, a4.y);
        pk.y = pack2bf(a4.z, a4.w);
        *(uint2*)&alds[r][c4] = pk;
    }

    f32x4 acc[4];
    #pragma unroll
    for (int nt = 0; nt < 4; ++nt) acc[nt] = (f32x4){0.f, 0.f, 0.f, 0.f};

    for (int k0 = 0; k0 < 192; k0 += 64) {
        __syncthreads();
        #pragma unroll
        for (int p = 0; p < 4; ++p) {
            int fid = tid + p * 256;
            int j = fid >> 4, k4 = (fid & 15) * 4;
            float4 w4 = *(const float4*)&w[(size_t)(col0 + j) * 192 + k0 + k4];
            uint2 pk;
            pk.x = pack2bf(w4.x, w4.y);
            pk.y = pack2bf(w4.z, w4.w);
            *(uint2*)&blds[j][k4] = pk;
        }
        __syncthreads();
        #pragma unroll
        for (int ks = 0; ks < 2; ++ks) {
            bf16x8 af = *(const bf16x8*)&alds[wv * 16 + qi][k0 + ks * 32 + g * 8];
            #pragma unroll
            for (int nt = 0; nt < 4; ++nt) {
                bf16x8 bf = *(const bf16x8*)&blds[nt * 16 + qi][ks * 32 + g * 8];
                acc[nt] = __builtin_amdgcn_mfma_f32_16x16x32_bf16(af, bf, acc[nt], 0, 0, 0);
            }
        }
    }

    #pragma unroll
    for (int nt = 0; nt < 4; ++nt) {
        int col = col0 + nt * 16 + qi;
        int three = col / 192;
        int rem = col - three * 192;
        int h = rem >> 5, c = rem & 31;
        unsigned short* dst = (three == 0) ? qout : ((three == 1) ? kout : vout);
        #pragma unroll
        for (int r = 0; r < 4; ++r) {
            int row = row0 + wv * 16 + 4 * g + r;
            int n = row / 1600, t = row - n * 1600;
            dst[((size_t)(n * 6 + h) * 1600 + t) * 32 + c] = f2bf(acc[nt][r]);
        }
    }
}

// ---------------------------------------------------------------------------
// Kernel 2: fused attention, bf16 MFMA, no-max unnormalized softmax.
// K staged via global_load_lds (linear [64][32]); P redistributed via
// per-wave LDS buffer (replaces bpermute); cvt_pk bf16 packing.
// ---------------------------------------------------------------------------
__global__ __launch_bounds__(256) void attn_kernel(
    const unsigned short* __restrict__ qw, const unsigned short* __restrict__ kw,
    const unsigned short* __restrict__ vw, const float* __restrict__ tt,
    const float* __restrict__ th, const int* __restrict__ hops,
    const float* __restrict__ alpha_p, float* __restrict__ aout)
{
    __shared__ __align__(16) unsigned short ks[64][32];   // K tile, linear (gload_lds)
    __shared__ __align__(16) unsigned short vts[32][72];  // V transposed, padded
    __shared__ __align__(16) unsigned int plds[4][16][36]; // per-wave P buffer
    __shared__ float ttl[128];
    __shared__ unsigned short fsps[1600];

    int b = blockIdx.x;
    int serial = (b & 7) * 150 + (b >> 3);   // XCD-contiguous nh chunks
    int nh = serial / 25;
    int qt = serial % 25;
    int h = nh % 6;
    int t0 = qt * 64;

    int tid = threadIdx.x;
    int lane = tid & 63, wv = tid >> 6;
    int g = lane >> 4, qi = lane & 15;

    const unsigned short* qb = qw + (size_t)nh * 1600 * 32;
    const unsigned short* kb = kw + (size_t)nh * 1600 * 32;
    const unsigned short* vb = vw + (size_t)nh * 1600 * 32;
    float* ab = aout + (size_t)nh * 1600 * 32;

    if (tid < 127) ttl[tid] = tt[h * 127 + tid];
    for (int s = tid; s < 1600; s += 256) {
        int fs = (s * 5243) >> 17;
        int ps = s - fs * 25;
        fsps[s] = (unsigned short)((fs << 5) | ps);
    }

    int tq = t0 + wv * 16 + qi;
    int ft = (tq * 5243) >> 17;
    int pt = tq - ft * 25;

    bf16x8 qfrag = *(const bf16x8*)&qb[(size_t)tq * 32 + g * 8];

    // static part of B_aug: k = g*8+j ; k in [4,29) -> hbl[pt*25 + (k-4)]
    unsigned int baug_hi[4], baug_lo[4];
    #pragma unroll
    for (int jj = 0; jj < 4; ++jj) {
        int k0 = g * 8 + 2 * jj, k1 = k0 + 1;
        float v0 = 0.f, v1 = 0.f;
        if (k0 >= 4 && k0 < 29) v0 = th[h * 5 + hops[pt * 25 + (k0 - 4)]];
        if (k1 >= 4 && k1 < 29) v1 = th[h * 5 + hops[pt * 25 + (k1 - 4)]];
        unsigned short h0 = f2bf(v0), h1 = f2bf(v1);
        unsigned short l0 = f2bf(v0 - bf2f(h0)), l1 = f2bf(v1 - bf2f(h1));
        baug_hi[jj] = (unsigned)h0 | ((unsigned)h1 << 16);
        baug_lo[jj] = (unsigned)l0 | ((unsigned)l1 << 16);
    }

    float l = 0.f;
    f32x4 O0 = {0.f, 0.f, 0.f, 0.f}, O1 = {0.f, 0.f, 0.f, 0.f};

    int srow = tid >> 2, sc8 = (tid & 3) * 8;

    for (int s0 = 0; s0 < 1600; s0 += 64) {
        __syncthreads();
        {   // stage K (global_load_lds, linear) and V (reg transpose, padded)
            __builtin_amdgcn_global_load_lds(
                (const __attribute__((address_space(1))) void*)
                    (kb + (size_t)(s0 + srow) * 32 + sc8),
                (__attribute__((address_space(3))) void*)
                    ((char*)&ks[0][0] + wv * 1024),
                16, 0, 0);
            union { uint4 u; unsigned short s[8]; } vv;
            vv.u = *(const uint4*)&vb[(size_t)(s0 + srow) * 32 + sc8];
            #pragma unroll
            for (int j = 0; j < 8; ++j) vts[sc8 + j][srow] = vv.s[j];
        }
        __syncthreads();

        int fs0 = fsps[s0] >> 5;

        // dynamic ttl slots (k=0..3) of B_aug, only g==0 lanes
        unsigned int bh0 = baug_hi[0], bh1 = baug_hi[1];
        unsigned int bl0 = baug_lo[0], bl1 = baug_lo[1];
        if (g == 0) {
            int base = ft - fs0 + 63;
            float tv0 = ttl[max(base, 0)];
            float tv1 = ttl[max(base - 1, 0)];
            float tv2 = ttl[max(base - 2, 0)];
            float tv3 = ttl[max(base - 3, 0)];
            unsigned short h0 = f2bf(tv0), h1 = f2bf(tv1), h2 = f2bf(tv2), h3 = f2bf(tv3);
            bh0 = (unsigned)h0 | ((unsigned)h1 << 16);
            bh1 = (unsigned)h2 | ((unsigned)h3 << 16);
            unsigned short l0s = f2bf(tv0 - bf2f(h0)), l1s = f2bf(tv1 - bf2f(h1));
            unsigned short l2s = f2bf(tv2 - bf2f(h2)), l3s = f2bf(tv3 - bf2f(h3));
            bl0 = (unsigned)l0s | ((unsigned)l1s << 16);
            bl1 = (unsigned)l2s | ((unsigned)l3s << 16);
        }
        uint4v bhiu = {bh0, bh1, baug_hi[2], baug_hi[3]};
        uint4v blou = {bl0, bl1, baug_lo[2], baug_lo[3]};
        bf16x8 bhif = __builtin_bit_cast(bf16x8, bhiu);
        bf16x8 blof = __builtin_bit_cast(bf16x8, blou);

        f32x4 sfr[4];
        #pragma unroll
        for (int sb = 0; sb < 4; ++sb) {
            int s = s0 + sb * 16 + qi;
            unsigned int uu = fsps[s];
            int dfs = (int)(uu >> 5) - fs0;
            int ps = (int)(uu & 31u);
            unsigned int a[4];
            #pragma unroll
            for (int jj = 0; jj < 4; ++jj) {
                int k0 = g * 8 + 2 * jj, k1 = k0 + 1;
                bool c0 = (k0 < 4) ? (dfs == k0) : (ps == k0 - 4);
                bool c1 = (k1 < 4) ? (dfs == k1) : (ps == k1 - 4);
                a[jj] = (c0 ? 0x3F80u : 0u) | (c1 ? 0x3F800000u : 0u);
            }
            uint4v au = {a[0], a[1], a[2], a[3]};
            bf16x8 af = __builtin_bit_cast(bf16x8, au);
            bf16x8 kf = *(const bf16x8*)&ks[sb * 16 + qi][g * 8];
            f32x4 cz = {0.f, 0.f, 0.f, 0.f};
            f32x4 cb = __builtin_amdgcn_mfma_f32_16x16x32_bf16(af, blof, cz, 0, 0, 0);
            cb = __builtin_amdgcn_mfma_f32_16x16x32_bf16(af, bhif, cb, 0, 0, 0);
            sfr[sb] = __builtin_amdgcn_mfma_f32_16x16x32_bf16(kf, qfrag, cb, 0, 0, 0);
        }

        // unnormalized softmax: p = 2^(sfr * SCALE * log2e); accumulate l.
        // pack to bf16 pairs and park in per-wave LDS in PV A-frag layout.
        #pragma unroll
        for (int sb = 0; sb < 4; ++sb) {
            float p0 = __builtin_exp2f(sfr[sb][0] * SC2F);
            float p1 = __builtin_exp2f(sfr[sb][1] * SC2F);
            float p2 = __builtin_exp2f(sfr[sb][2] * SC2F);
            float p3 = __builtin_exp2f(sfr[sb][3] * SC2F);
            l += (p0 + p1) + (p2 + p3);
            uint2 wp;
            wp.x = cvt_pk_bf16(p0, p1);
            wp.y = cvt_pk_bf16(p2, p3);
            *(uint2*)&plds[wv][qi][sb * 8 + 2 * g] = wp;
        }

        #pragma unroll
        for (int c = 0; c < 2; ++c) {
            bf16x8 paf = *(const bf16x8*)&plds[wv][qi][c * 16 + 4 * g];
            bf16x8 v0f = *(const bf16x8*)&vts[qi][c * 32 + g * 8];
            bf16x8 v1f = *(const bf16x8*)&vts[16 + qi][c * 32 + g * 8];
            O0 = __builtin_amdgcn_mfma_f32_16x16x32_bf16(paf, v0f, O0, 0, 0, 0);
            O1 = __builtin_amdgcn_mfma_f32_16x16x32_bf16(paf, v1f, O1, 0, 0, 0);
        }
    }

    l += __shfl_xor(l, 16, 64);
    l += __shfl_xor(l, 32, 64);
    float alpha = alpha_p[0];
    float winv = alpha / l;
    int trow = t0 + wv * 16;
    #pragma unroll
    for (int r = 0; r < 4; ++r) {
        float wr = __uint_as_float(
            __builtin_amdgcn_ds_bpermute((4 * g + r) << 2, __float_as_uint(winv)));
        ab[(size_t)(trow + 4 * g + r) * 32 + qi] = O0[r] * wr;
        ab[(size_t)(trow + 4 * g + r) * 32 + 16 + qi] = O1[r] * wr;
    }
}

// ---------------------------------------------------------------------------
// Kernel 3a: relational term. (unchanged)
// ---------------------------------------------------------------------------
__global__ __launch_bounds__(256) void rel_kernel(
    const float* __restrict__ ab, const unsigned short* __restrict__ vw,
    const float* __restrict__ outer, unsigned short* __restrict__ comb)
{
    __shared__ float olds[25][26];
    __shared__ unsigned short vlds[25][32];
    int b = blockIdx.x;
    int n = b / 384;
    int h = (b / 64) % 6;
    int f = b & 63;
    int tid = threadIdx.x;

    for (int e = tid; e < 625; e += 256) olds[e / 25][e % 25] = outer[h * 625 + e];
    size_t vbase = ((size_t)(n * 6 + h) * 1600 + f * 25) * 32;
    for (int e = tid; e < 400; e += 256)
        ((unsigned int*)&vlds[0][0])[e] = *(const unsigned int*)&vw[vbase + e * 2];
    __syncthreads();

    size_t abase = vbase;
    size_t cbase = ((size_t)n * 1600 + f * 25) * 192 + h * 32;
    for (int e = tid; e < 800; e += 256) {
        int p = e >> 5, c = e & 31;
        float s = ab[abase + e];
        #pragma unroll
        for (int q = 0; q < 25; ++q) s += olds[p][q] * bf2f(vlds[q][c]);
        comb[cbase + (size_t)p * 192 + c] = f2bf(s);
    }
}

// ---------------------------------------------------------------------------
// Kernel 3b: final projection, bf16 MFMA GEMM. (unchanged)
// ---------------------------------------------------------------------------
__global__ __launch_bounds__(256) void proj_gemm_kernel(
    const unsigned short* __restrict__ comb, const float* __restrict__ pw,
    const float* __restrict__ pb, float* __restrict__ out)
{
    __shared__ __align__(16) unsigned short alds[64][200];
    __shared__ __align__(16) unsigned short blds[64][72];

    int b = blockIdx.x;
    int bm = b % 200, bn = b / 200;
    int row0 = bm * 64, col0 = bn * 64;
    int tid = threadIdx.x, lane = tid & 63, wv = tid >> 6;
    int g = lane >> 4, qi = lane & 15;

    #pragma unroll
    for (int p = 0; p < 6; ++p) {
        int fid = tid + p * 256;
        int r = fid / 24, c8 = (fid % 24) * 8;
        *(uint4*)&alds[r][c8] = *(const uint4*)&comb[(size_t)(row0 + r) * 192 + c8];
    }

    f32x4 acc[4];
    #pragma unroll
    for (int nt = 0; nt < 4; ++nt) acc[nt] = (f32x4){0.f, 0.f, 0.f, 0.f};

    for (int k0 = 0; k0 < 192; k0 += 64) {
        __syncthreads();
        #pragma unroll
        for (int p = 0; p < 4; ++p) {
            int fid = tid + p * 256;
            int j = fid >> 4, k4 = (fid & 15) * 4;
            float4 w4 = *(const float4*)&pw[(size_t)(col0 + j) * 192 + k0 + k4];
            uint2 pk;
            pk.x = pack2bf(w4.x, w4.y);
            pk.y = pack2bf(w4.z, w4.w);
            *(uint2*)&blds[j][k4] = pk;
        }
        __syncthreads();
        #pragma unroll
        for (int ks = 0; ks < 2; ++ks) {
            bf16x8 af = *(const bf16x8*)&alds[wv * 16 + qi][k0 + ks * 32 + g * 8];
            #pragma unroll
            for (int nt = 0; nt < 4; ++nt) {
                bf16x8 bf = *(const bf16x8*)&blds[nt * 16 + qi][ks * 32 + g * 8];
                acc[nt] = __builtin_amdgcn_mfma_f32_16x16x32_bf16(af, bf, acc[nt], 0, 0, 0);
            }
        }
    }

    #pragma unroll
    for (int nt = 0; nt < 4; ++nt) {
        int col = col0 + nt * 16 + qi;
        float bias = pb[col];
        #pragma unroll
        for (int r = 0; r < 4; ++r) {
            int row = row0 + wv * 16 + 4 * g + r;
            out[(size_t)row * 192 + col] = acc[nt][r] + bias;
        }
    }
}

// ---------------------------------------------------------------------------
extern "C" void kernel_launch(void* const* d_in, const int* in_sizes, int n_in,
                              void* d_out, int out_size, void* d_ws, size_t ws_size,
                              hipStream_t stream)
{
    const float* x      = (const float*)d_in[0];
    const float* qkv_w  = (const float*)d_in[1];
    const float* proj_w = (const float*)d_in[2];
    const float* proj_b = (const float*)d_in[3];
    const float* t_w1   = (const float*)d_in[4];
    const float* t_b1   = (const float*)d_in[5];
    const float* t_w2   = (const float*)d_in[6];
    const float* t_b2   = (const float*)d_in[7];
    const float* h_w1   = (const float*)d_in[8];
    const float* h_b1   = (const float*)d_in[9];
    const float* h_w2   = (const float*)d_in[10];
    const float* h_b2   = (const float*)d_in[11];
    const float* outer  = (const float*)d_in[12];
    const float* alpha  = (const float*)d_in[13];
    const int*   hops   = (const int*)d_in[14];
    float* out = (float*)d_out;

    char* w8 = (char*)d_ws;
    float* tt = (float*)w8;                      // 762 floats
    float* th = tt + 762;                        // 30 floats
    unsigned short* qb = (unsigned short*)(w8 + 4096);
    unsigned short* kb = qb + 2457600;
    unsigned short* vb = kb + 2457600;
    float* ab = (float*)(w8 + 4096 + 3 * 4915200);
    unsigned short* comb = qb;                   // reuse q buffer (dead after attn)

    bias_tables_kernel<<<132, 192, 0, stream>>>(t_w1, t_b1, t_w2, t_b2,
                                                h_w1, h_b1, h_w2, h_b2, tt, th);
    qkv_gemm_kernel<<<1800, 256, 0, stream>>>(x, qkv_w, qb, kb, vb);
    attn_kernel<<<1200, 256, 0, stream>>>(qb, kb, vb, tt, th, hops, alpha, ab);
    rel_kernel<<<3072, 256, 0, stream>>>(ab, vb, outer, comb);
    proj_gemm_kernel<<<600, 256, 0, stream>>>(comb, proj_w, proj_b, out);
}

// Round 9
// 117.178 us; speedup vs baseline: 7.4545x; 1.2860x over previous
//
#include <hip/hip_runtime.h>
#include <math.h>

#define N_ 8
#define F_ 64
#define P_ 25
#define H_ 6
#define D_ 192
#define HD_ 32
#define T_ 1600
#define SCALE_ 0.17677669529663687f
#define SC2F 0.25503486f   // SCALE * log2(e)

typedef short bf16x8 __attribute__((ext_vector_type(8)));
typedef float f32x4 __attribute__((ext_vector_type(4)));
typedef unsigned int uint4v __attribute__((ext_vector_type(4)));

__device__ __forceinline__ unsigned short f2bf(float f) {
    unsigned int u = __float_as_uint(f);
    u += 0x7fffu + ((u >> 16) & 1u);
    return (unsigned short)(u >> 16);
}
__device__ __forceinline__ float bf2f(unsigned short s) {
    return __uint_as_float(((unsigned int)s) << 16);
}
__device__ __forceinline__ unsigned int pack2bf(float lo, float hi) {
    return (unsigned int)f2bf(lo) | ((unsigned int)f2bf(hi) << 16);
}
__device__ __forceinline__ unsigned int cvt_pk_bf16(float lo, float hi) {
    unsigned int r;
    asm("v_cvt_pk_bf16_f32 %0, %1, %2" : "=v"(r) : "v"(lo), "v"(hi));
    return r;
}

// ---------------------------------------------------------------------------
// Kernel 0: bias MLP tables, PRE-SCALED by SC2F (softmax is scale-invariant).
// ---------------------------------------------------------------------------
__global__ void bias_tables_kernel(
    const float* __restrict__ t_w1, const float* __restrict__ t_b1,
    const float* __restrict__ t_w2, const float* __restrict__ t_b2,
    const float* __restrict__ h_w1, const float* __restrict__ h_b1,
    const float* __restrict__ h_w2, const float* __restrict__ h_b2,
    float* __restrict__ tt, float* __restrict__ th)
{
    __shared__ float hid[192];
    int b = blockIdx.x;
    bool is_t = (b < 127);
    float pos = is_t ? (float)(b - 63) : (float)(b - 127);
    const float* w1 = is_t ? t_w1 : h_w1;
    const float* b1 = is_t ? t_b1 : h_b1;
    const float* w2 = is_t ? t_w2 : h_w2;
    const float* b2 = is_t ? t_b2 : h_b2;
    int t = threadIdx.x;
    if (t < 192) hid[t] = fmaxf(pos * w1[t] + b1[t], 0.0f);
    __syncthreads();
    if (t < 6) {
        float s = b2[t];
        for (int j = 0; j < 192; ++j) s += w2[t * 192 + j] * hid[j];
        s *= SC2F;
        if (is_t) tt[t * 127 + b] = s;
        else      th[t * 5 + (b - 127)] = s;
    }
}

// ---------------------------------------------------------------------------
// Kernel 0b: precompute onehot A-fragments for the bias aug-MFMA.
// augA[(tau*4 + sb)*64 + lane][0..3] : block-invariant, 102.4 KB, L2-hot.
// ---------------------------------------------------------------------------
__global__ __launch_bounds__(256) void aug_build_kernel(unsigned int* __restrict__ augA)
{
    int tau = blockIdx.x;
    int sb = threadIdx.x >> 6, lane = threadIdx.x & 63;
    int g = lane >> 4, qi = lane & 15;
    int s = tau * 64 + sb * 16 + qi;
    int fs = (s * 5243) >> 17;
    int ps = s - fs * 25;
    int fs0 = ((tau * 64) * 5243) >> 17;
    int dfs = fs - fs0;
    unsigned int a[4];
    #pragma unroll
    for (int jj = 0; jj < 4; ++jj) {
        int k0 = g * 8 + 2 * jj, k1 = k0 + 1;
        bool c0 = (k0 < 4) ? (dfs == k0) : (ps == k0 - 4);
        bool c1 = (k1 < 4) ? (dfs == k1) : (ps == k1 - 4);
        a[jj] = (c0 ? 0x3F80u : 0u) | (c1 ? 0x3F800000u : 0u);
    }
    uint4v w = {a[0], a[1], a[2], a[3]};
    *(uint4v*)&augA[((size_t)(tau * 4 + sb) * 64 + lane) * 4] = w;
}

// ---------------------------------------------------------------------------
// Kernel 1: QKV projection, bf16 MFMA GEMM. Q pre-scaled by SC2F (fp32).
// ---------------------------------------------------------------------------
__global__ __launch_bounds__(256) void qkv_gemm_kernel(
    const float* __restrict__ x, const float* __restrict__ w,
    unsigned short* __restrict__ qout, unsigned short* __restrict__ kout,
    unsigned short* __restrict__ vout)
{
    __shared__ __align__(16) unsigned short alds[64][200];
    __shared__ __align__(16) unsigned short blds[64][72];

    int b = blockIdx.x;
    int bm = b % 200, bn = b / 200;
    int row0 = bm * 64, col0 = bn * 64;
    int tid = threadIdx.x, lane = tid & 63, wv = tid >> 6;
    int g = lane >> 4, qi = lane & 15;

    #pragma unroll
    for (int p = 0; p < 12; ++p) {
        int fid = tid + p * 256;
        int r = fid / 48, c4 = (fid % 48) * 4;
        float4 a4 = *(const float4*)&x[(size_t)(row0 + r) * 192 + c4];
        uint2 pk;
        pk.x = pack2bf(a4.x, a4.y);
        pk.y = pack2bf(a4.z, a4.w);
        *(uint2*)&alds[r][c4] = pk;
    }

    f32x4 acc[4];
    #pragma unroll
    for (int nt = 0; nt < 4; ++nt) acc[nt] = (f32x4){0.f, 0.f, 0.f, 0.f};

    for (int k0 = 0; k0 < 192; k0 += 64) {
        __syncthreads();
        #pragma unroll
        for (int p = 0; p < 4; ++p) {
            int fid = tid + p * 256;
            int j = fid >> 4, k4 = (fid & 15) * 4;
            float4 w4 = *(const float4*)&w[(size_t)(col0 + j) * 192 + k0 + k4];
            uint2 pk;
            pk.x = pack2bf(w4.x, w4.y);
            pk.y = pack2bf(w4.z, w4.w);
            *(uint2*)&blds[j][k4] = pk;
        }
        __syncthreads();
        #pragma unroll
        for (int ks = 0; ks < 2; ++ks) {
            bf16x8 af = *(const bf16x8*)&alds[wv * 16 + qi][k0 + ks * 32 + g * 8];
            #pragma unroll
            for (int nt = 0; nt < 4; ++nt) {
                bf16x8 bf = *(const bf16x8*)&blds[nt * 16 + qi][ks * 32 + g * 8];
                acc[nt] = __builtin_amdgcn_mfma_f32_16x16x32_bf16(af, bf, acc[nt], 0, 0, 0);
            }
        }
    }

    #pragma unroll
    for (int nt = 0; nt < 4; ++nt) {
        int col = col0 + nt * 16 + qi;
        int three = col / 192;
        int rem = col - three * 192;
        int h = rem >> 5, c = rem & 31;
        unsigned short* dst = (three == 0) ? qout : ((three == 1) ? kout : vout);
        float scl = (three == 0) ? SC2F : 1.0f;
        #pragma unroll
        for (int r = 0; r < 4; ++r) {
            int row = row0 + wv * 16 + 4 * g + r;
            int n = row / 1600, t = row - n * 1600;
            dst[((size_t)(n * 6 + h) * 1600 + t) * 32 + c] = f2bf(acc[nt][r] * scl);
        }
    }
}

// ---------------------------------------------------------------------------
// Kernel 2: fused attention. Double-buffered K/V (1 barrier/tile), table-driven
// onehot A-frags (reg double-buffered), no-max exp2 softmax, LDS P-redistribute.
// K back in padded [64][40] (conflict-free ds_read_b128).
// ---------------------------------------------------------------------------
__global__ __launch_bounds__(256) void attn_kernel(
    const unsigned short* __restrict__ qw, const unsigned short* __restrict__ kw,
    const unsigned short* __restrict__ vw, const float* __restrict__ tt,
    const float* __restrict__ th, const int* __restrict__ hops,
    const unsigned int* __restrict__ augA,
    const float* __restrict__ alpha_p, float* __restrict__ aout)
{
    __shared__ __align__(16) unsigned short ks[2][64][40];   // K, padded rows
    __shared__ __align__(16) unsigned short vts[2][32][72];  // V^T, padded
    __shared__ __align__(16) unsigned int plds[4][16][36];   // per-wave P buffer
    __shared__ float ttl[128];

    int b = blockIdx.x;
    int serial = (b & 7) * 150 + (b >> 3);   // XCD-contiguous nh chunks
    int nh = serial / 25;
    int qt = serial % 25;
    int h = nh % 6;
    int t0 = qt * 64;

    int tid = threadIdx.x;
    int lane = tid & 63, wv = tid >> 6;
    int g = lane >> 4, qi = lane & 15;

    const unsigned short* qb = qw + (size_t)nh * 51200;
    const unsigned short* kb = kw + (size_t)nh * 51200;
    const unsigned short* vb = vw + (size_t)nh * 51200;
    float* ab = aout + (size_t)nh * 51200;

    if (tid < 127) ttl[tid] = tt[h * 127 + tid];

    int tq = t0 + wv * 16 + qi;
    int ft = (tq * 5243) >> 17;
    int pt = tq - ft * 25;

    bf16x8 qfrag = *(const bf16x8*)&qb[(size_t)tq * 32 + g * 8];

    // static part of B_aug (hop bias, pre-scaled th), hi+lo split
    unsigned int baug_hi[4], baug_lo[4];
    #pragma unroll
    for (int jj = 0; jj < 4; ++jj) {
        int k0 = g * 8 + 2 * jj, k1 = k0 + 1;
        float v0 = 0.f, v1 = 0.f;
        if (k0 >= 4 && k0 < 29) v0 = th[h * 5 + hops[pt * 25 + (k0 - 4)]];
        if (k1 >= 4 && k1 < 29) v1 = th[h * 5 + hops[pt * 25 + (k1 - 4)]];
        unsigned short h0 = f2bf(v0), h1 = f2bf(v1);
        unsigned short l0 = f2bf(v0 - bf2f(h0)), l1 = f2bf(v1 - bf2f(h1));
        baug_hi[jj] = (unsigned)h0 | ((unsigned)h1 << 16);
        baug_lo[jj] = (unsigned)l0 | ((unsigned)l1 << 16);
    }

    float l = 0.f;
    f32x4 O0 = {0.f, 0.f, 0.f, 0.f}, O1 = {0.f, 0.f, 0.f, 0.f};

    int srow = tid >> 2, sc8 = (tid & 3) * 8;
    const uint4v* augp = (const uint4v*)augA;

    // ---- prologue: stage tile 0 into buffer 0, prefetch aug regs ----
    {
        uint4 k4 = *(const uint4*)&kb[(size_t)srow * 32 + sc8];
        union { uint4 u; unsigned short s[8]; } vv;
        vv.u = *(const uint4*)&vb[(size_t)srow * 32 + sc8];
        *(uint4*)&ks[0][srow][sc8] = k4;
        #pragma unroll
        for (int j = 0; j < 8; ++j) vts[0][sc8 + j][srow] = vv.s[j];
    }
    uint4v augr[4];
    #pragma unroll
    for (int sb = 0; sb < 4; ++sb) augr[sb] = augp[(size_t)sb * 64 + lane];
    __syncthreads();

    for (int tau = 0; tau < 25; ++tau) {
        int cur = tau & 1, nxt = cur ^ 1;
        int s0 = tau * 64;
        bool more = (tau < 24);

        // issue next tile's loads early (latency hides under compute)
        uint4 kreg = {0, 0, 0, 0}, vreg = {0, 0, 0, 0};
        uint4v augn[4];
        if (more) {
            kreg = *(const uint4*)&kb[(size_t)(s0 + 64 + srow) * 32 + sc8];
            vreg = *(const uint4*)&vb[(size_t)(s0 + 64 + srow) * 32 + sc8];
            #pragma unroll
            for (int sb = 0; sb < 4; ++sb)
                augn[sb] = augp[(size_t)((tau + 1) * 4 + sb) * 64 + lane];
        }

        int fs0 = (s0 * 5243) >> 17;

        // dynamic ttl slots (k=0..3) of B_aug, only g==0 lanes (pre-scaled tt)
        unsigned int bh0 = baug_hi[0], bh1 = baug_hi[1];
        unsigned int bl0 = baug_lo[0], bl1 = baug_lo[1];
        if (g == 0) {
            int base = ft - fs0 + 63;
            float tv0 = ttl[max(base, 0)];
            float tv1 = ttl[max(base - 1, 0)];
            float tv2 = ttl[max(base - 2, 0)];
            float tv3 = ttl[max(base - 3, 0)];
            unsigned short h0 = f2bf(tv0), h1 = f2bf(tv1), h2 = f2bf(tv2), h3 = f2bf(tv3);
            bh0 = (unsigned)h0 | ((unsigned)h1 << 16);
            bh1 = (unsigned)h2 | ((unsigned)h3 << 16);
            unsigned short l0s = f2bf(tv0 - bf2f(h0)), l1s = f2bf(tv1 - bf2f(h1));
            unsigned short l2s = f2bf(tv2 - bf2f(h2)), l3s = f2bf(tv3 - bf2f(h3));
            bl0 = (unsigned)l0s | ((unsigned)l1s << 16);
            bl1 = (unsigned)l2s | ((unsigned)l3s << 16);
        }
        uint4v bhiu = {bh0, bh1, baug_hi[2], baug_hi[3]};
        uint4v blou = {bl0, bl1, baug_lo[2], baug_lo[3]};
        bf16x8 bhif = __builtin_bit_cast(bf16x8, bhiu);
        bf16x8 blof = __builtin_bit_cast(bf16x8, blou);

        // QK^T + bias via table-driven aug-MFMA
        f32x4 sfr[4];
        #pragma unroll
        for (int sb = 0; sb < 4; ++sb) {
            bf16x8 af = __builtin_bit_cast(bf16x8, augr[sb]);
            bf16x8 kf = *(const bf16x8*)&ks[cur][sb * 16 + qi][g * 8];
            f32x4 cz = {0.f, 0.f, 0.f, 0.f};
            f32x4 cb = __builtin_amdgcn_mfma_f32_16x16x32_bf16(af, blof, cz, 0, 0, 0);
            cb = __builtin_amdgcn_mfma_f32_16x16x32_bf16(af, bhif, cb, 0, 0, 0);
            sfr[sb] = __builtin_amdgcn_mfma_f32_16x16x32_bf16(kf, qfrag, cb, 0, 0, 0);
        }

        // unnormalized softmax (logits already in log2 units): p = 2^sfr
        #pragma unroll
        for (int sb = 0; sb < 4; ++sb) {
            float p0 = __builtin_exp2f(sfr[sb][0]);
            float p1 = __builtin_exp2f(sfr[sb][1]);
            float p2 = __builtin_exp2f(sfr[sb][2]);
            float p3 = __builtin_exp2f(sfr[sb][3]);
            l += (p0 + p1) + (p2 + p3);
            uint2 wp;
            wp.x = cvt_pk_bf16(p0, p1);
            wp.y = cvt_pk_bf16(p2, p3);
            *(uint2*)&plds[wv][qi][sb * 8 + 2 * g] = wp;
        }

        #pragma unroll
        for (int c = 0; c < 2; ++c) {
            bf16x8 paf = *(const bf16x8*)&plds[wv][qi][c * 16 + 4 * g];
            bf16x8 v0f = *(const bf16x8*)&vts[cur][qi][c * 32 + g * 8];
            bf16x8 v1f = *(const bf16x8*)&vts[cur][16 + qi][c * 32 + g * 8];
            O0 = __builtin_amdgcn_mfma_f32_16x16x32_bf16(paf, v0f, O0, 0, 0, 0);
            O1 = __builtin_amdgcn_mfma_f32_16x16x32_bf16(paf, v1f, O1, 0, 0, 0);
        }

        // late LDS writes for tile tau+1 (T14 split)
        if (more) {
            *(uint4*)&ks[nxt][srow][sc8] = kreg;
            union { uint4 u; unsigned short s[8]; } vv;
            vv.u = vreg;
            #pragma unroll
            for (int j = 0; j < 8; ++j) vts[nxt][sc8 + j][srow] = vv.s[j];
            #pragma unroll
            for (int sb = 0; sb < 4; ++sb) augr[sb] = augn[sb];
        }
        __syncthreads();
    }

    l += __shfl_xor(l, 16, 64);
    l += __shfl_xor(l, 32, 64);
    float alpha = alpha_p[0];
    float winv = alpha / l;
    int trow = t0 + wv * 16;
    #pragma unroll
    for (int r = 0; r < 4; ++r) {
        float wr = __uint_as_float(
            __builtin_amdgcn_ds_bpermute((4 * g + r) << 2, __float_as_uint(winv)));
        ab[(size_t)(trow + 4 * g + r) * 32 + qi] = O0[r] * wr;
        ab[(size_t)(trow + 4 * g + r) * 32 + 16 + qi] = O1[r] * wr;
    }
}

// ---------------------------------------------------------------------------
// Kernel 3a: relational term. (unchanged)
// ---------------------------------------------------------------------------
__global__ __launch_bounds__(256) void rel_kernel(
    const float* __restrict__ ab, const unsigned short* __restrict__ vw,
    const float* __restrict__ outer, unsigned short* __restrict__ comb)
{
    __shared__ float olds[25][26];
    __shared__ unsigned short vlds[25][32];
    int b = blockIdx.x;
    int n = b / 384;
    int h = (b / 64) % 6;
    int f = b & 63;
    int tid = threadIdx.x;

    for (int e = tid; e < 625; e += 256) olds[e / 25][e % 25] = outer[h * 625 + e];
    size_t vbase = ((size_t)(n * 6 + h) * 1600 + f * 25) * 32;
    for (int e = tid; e < 400; e += 256)
        ((unsigned int*)&vlds[0][0])[e] = *(const unsigned int*)&vw[vbase + e * 2];
    __syncthreads();

    size_t abase = vbase;
    size_t cbase = ((size_t)n * 1600 + f * 25) * 192 + h * 32;
    for (int e = tid; e < 800; e += 256) {
        int p = e >> 5, c = e & 31;
        float s = ab[abase + e];
        #pragma unroll
        for (int q = 0; q < 25; ++q) s += olds[p][q] * bf2f(vlds[q][c]);
        comb[cbase + (size_t)p * 192 + c] = f2bf(s);
    }
}

// ---------------------------------------------------------------------------
// Kernel 3b: final projection, bf16 MFMA GEMM. (unchanged)
// ---------------------------------------------------------------------------
__global__ __launch_bounds__(256) void proj_gemm_kernel(
    const unsigned short* __restrict__ comb, const float* __restrict__ pw,
    const float* __restrict__ pb, float* __restrict__ out)
{
    __shared__ __align__(16) unsigned short alds[64][200];
    __shared__ __align__(16) unsigned short blds[64][72];

    int b = blockIdx.x;
    int bm = b % 200, bn = b / 200;
    int row0 = bm * 64, col0 = bn * 64;
    int tid = threadIdx.x, lane = tid & 63, wv = tid >> 6;
    int g = lane >> 4, qi = lane & 15;

    #pragma unroll
    for (int p = 0; p < 6; ++p) {
        int fid = tid + p * 256;
        int r = fid / 24, c8 = (fid % 24) * 8;
        *(uint4*)&alds[r][c8] = *(const uint4*)&comb[(size_t)(row0 + r) * 192 + c8];
    }

    f32x4 acc[4];
    #pragma unroll
    for (int nt = 0; nt < 4; ++nt) acc[nt] = (f32x4){0.f, 0.f, 0.f, 0.f};

    for (int k0 = 0; k0 < 192; k0 += 64) {
        __syncthreads();
        #pragma unroll
        for (int p = 0; p < 4; ++p) {
            int fid = tid + p * 256;
            int j = fid >> 4, k4 = (fid & 15) * 4;
            float4 w4 = *(const float4*)&pw[(size_t)(col0 + j) * 192 + k0 + k4];
            uint2 pk;
            pk.x = pack2bf(w4.x, w4.y);
            pk.y = pack2bf(w4.z, w4.w);
            *(uint2*)&blds[j][k4] = pk;
        }
        __syncthreads();
        #pragma unroll
        for (int ks = 0; ks < 2; ++ks) {
            bf16x8 af = *(const bf16x8*)&alds[wv * 16 + qi][k0 + ks * 32 + g * 8];
            #pragma unroll
            for (int nt = 0; nt < 4; ++nt) {
                bf16x8 bf = *(const bf16x8*)&blds[nt * 16 + qi][ks * 32 + g * 8];
                acc[nt] = __builtin_amdgcn_mfma_f32_16x16x32_bf16(af, bf, acc[nt], 0, 0, 0);
            }
        }
    }

    #pragma unroll
    for (int nt = 0; nt < 4; ++nt) {
        int col = col0 + nt * 16 + qi;
        float bias = pb[col];
        #pragma unroll
        for (int r = 0; r < 4; ++r) {
            int row = row0 + wv * 16 + 4 * g + r;
            out[(size_t)row * 192 + col] = acc[nt][r] + bias;
        }
    }
}

// ---------------------------------------------------------------------------
extern "C" void kernel_launch(void* const* d_in, const int* in_sizes, int n_in,
                              void* d_out, int out_size, void* d_ws, size_t ws_size,
                              hipStream_t stream)
{
    const float* x      = (const float*)d_in[0];
    const float* qkv_w  = (const float*)d_in[1];
    const float* proj_w = (const float*)d_in[2];
    const float* proj_b = (const float*)d_in[3];
    const float* t_w1   = (const float*)d_in[4];
    const float* t_b1   = (const float*)d_in[5];
    const float* t_w2   = (const float*)d_in[6];
    const float* t_b2   = (const float*)d_in[7];
    const float* h_w1   = (const float*)d_in[8];
    const float* h_b1   = (const float*)d_in[9];
    const float* h_w2   = (const float*)d_in[10];
    const float* h_b2   = (const float*)d_in[11];
    const float* outer  = (const float*)d_in[12];
    const float* alpha  = (const float*)d_in[13];
    const int*   hops   = (const int*)d_in[14];
    float* out = (float*)d_out;

    char* w8 = (char*)d_ws;
    float* tt = (float*)w8;                              // 762 floats
    float* th = tt + 762;                                // 30 floats
    unsigned int* augA = (unsigned int*)(w8 + 4096);     // 102400 B
    unsigned short* qb = (unsigned short*)(w8 + 4096 + 102400);
    unsigned short* kb = qb + 2457600;
    unsigned short* vb = kb + 2457600;
    float* ab = (float*)(w8 + 4096 + 102400 + 3 * 4915200);
    unsigned short* comb = qb;                           // reuse q buffer

    bias_tables_kernel<<<132, 192, 0, stream>>>(t_w1, t_b1, t_w2, t_b2,
                                                h_w1, h_b1, h_w2, h_b2, tt, th);
    aug_build_kernel<<<25, 256, 0, stream>>>(augA);
    qkv_gemm_kernel<<<1800, 256, 0, stream>>>(x, qkv_w, qb, kb, vb);
    attn_kernel<<<1200, 256, 0, stream>>>(qb, kb, vb, tt, th, hops, augA, alpha, ab);
    rel_kernel<<<3072, 256, 0, stream>>>(ab, vb, outer, comb);
    proj_gemm_kernel<<<600, 256, 0, stream>>>(comb, proj_w, proj_b, out);
}

// Round 10
// 107.140 us; speedup vs baseline: 8.1529x; 1.0937x over previous
//
#include <hip/hip_runtime.h>
#include <math.h>

#define N_ 8
#define F_ 64
#define P_ 25
#define H_ 6
#define D_ 192
#define HD_ 32
#define T_ 1600
#define SC2F 0.25503486f   // SCALE * log2(e)

typedef short bf16x8 __attribute__((ext_vector_type(8)));
typedef float f32x4 __attribute__((ext_vector_type(4)));
typedef unsigned int uint4v __attribute__((ext_vector_type(4)));

__device__ __forceinline__ unsigned short f2bf(float f) {
    unsigned int u = __float_as_uint(f);
    u += 0x7fffu + ((u >> 16) & 1u);
    return (unsigned short)(u >> 16);
}
__device__ __forceinline__ float bf2f(unsigned short s) {
    return __uint_as_float(((unsigned int)s) << 16);
}
__device__ __forceinline__ unsigned int pack2bf(float lo, float hi) {
    return (unsigned int)f2bf(lo) | ((unsigned int)f2bf(hi) << 16);
}
__device__ __forceinline__ unsigned int cvt_pk_bf16(float lo, float hi) {
    unsigned int r;
    asm("v_cvt_pk_bf16_f32 %0, %1, %2" : "=v"(r) : "v"(lo), "v"(hi));
    return r;
}

// ---------------------------------------------------------------------------
// Kernel 0: bias MLP tables, PRE-SCALED by SC2F.
// ---------------------------------------------------------------------------
__global__ void bias_tables_kernel(
    const float* __restrict__ t_w1, const float* __restrict__ t_b1,
    const float* __restrict__ t_w2, const float* __restrict__ t_b2,
    const float* __restrict__ h_w1, const float* __restrict__ h_b1,
    const float* __restrict__ h_w2, const float* __restrict__ h_b2,
    float* __restrict__ tt, float* __restrict__ th)
{
    __shared__ float hid[192];
    int b = blockIdx.x;
    bool is_t = (b < 127);
    float pos = is_t ? (float)(b - 63) : (float)(b - 127);
    const float* w1 = is_t ? t_w1 : h_w1;
    const float* b1 = is_t ? t_b1 : h_b1;
    const float* w2 = is_t ? t_w2 : h_w2;
    const float* b2 = is_t ? t_b2 : h_b2;
    int t = threadIdx.x;
    if (t < 192) hid[t] = fmaxf(pos * w1[t] + b1[t], 0.0f);
    __syncthreads();
    if (t < 6) {
        float s = b2[t];
        for (int j = 0; j < 192; ++j) s += w2[t * 192 + j] * hid[j];
        s *= SC2F;
        if (is_t) tt[t * 127 + b] = s;
        else      th[t * 5 + (b - 127)] = s;
    }
}

// ---------------------------------------------------------------------------
// Kernel 0b: pack ttl table into (bf16(tt[i]), bf16(tt[i-1])) hi/lo u32 pairs.
// ---------------------------------------------------------------------------
__global__ void ttpack_kernel(const float* __restrict__ tt,
                              unsigned int* __restrict__ hi,
                              unsigned int* __restrict__ lo)
{
    int h = blockIdx.x;
    int i = threadIdx.x;
    if (i >= 127) return;
    float a = tt[h * 127 + i];
    float b = tt[h * 127 + max(i - 1, 0)];
    unsigned short ha = f2bf(a), hb = f2bf(b);
    hi[h * 127 + i] = (unsigned)ha | ((unsigned)hb << 16);
    lo[h * 127 + i] = (unsigned)f2bf(a - bf2f(ha)) |
                      ((unsigned)f2bf(b - bf2f(hb)) << 16);
}

// ---------------------------------------------------------------------------
// Kernel 0c: precompute onehot A-fragments for the bias aug-MFMA.
// ---------------------------------------------------------------------------
__global__ __launch_bounds__(256) void aug_build_kernel(unsigned int* __restrict__ augA)
{
    int tau = blockIdx.x;
    int sb = threadIdx.x >> 6, lane = threadIdx.x & 63;
    int g = lane >> 4, qi = lane & 15;
    int s = tau * 64 + sb * 16 + qi;
    int fs = (s * 5243) >> 17;
    int ps = s - fs * 25;
    int fs0 = ((tau * 64) * 5243) >> 17;
    int dfs = fs - fs0;
    unsigned int a[4];
    #pragma unroll
    for (int jj = 0; jj < 4; ++jj) {
        int k0 = g * 8 + 2 * jj, k1 = k0 + 1;
        bool c0 = (k0 < 4) ? (dfs == k0) : (ps == k0 - 4);
        bool c1 = (k1 < 4) ? (dfs == k1) : (ps == k1 - 4);
        a[jj] = (c0 ? 0x3F80u : 0u) | (c1 ? 0x3F800000u : 0u);
    }
    uint4v w = {a[0], a[1], a[2], a[3]};
    *(uint4v*)&augA[((size_t)(tau * 4 + sb) * 64 + lane) * 4] = w;
}

// ---------------------------------------------------------------------------
// Kernel 1: QKV projection, bf16 MFMA GEMM. Q pre-scaled by SC2F.
// ---------------------------------------------------------------------------
__global__ __launch_bounds__(256) void qkv_gemm_kernel(
    const float* __restrict__ x, const float* __restrict__ w,
    unsigned short* __restrict__ qout, unsigned short* __restrict__ kout,
    unsigned short* __restrict__ vout)
{
    __shared__ __align__(16) unsigned short alds[64][200];
    __shared__ __align__(16) unsigned short blds[64][72];

    int b = blockIdx.x;
    int bm = b % 200, bn = b / 200;
    int row0 = bm * 64, col0 = bn * 64;
    int tid = threadIdx.x, lane = tid & 63, wv = tid >> 6;
    int g = lane >> 4, qi = lane & 15;

    #pragma unroll
    for (int p = 0; p < 12; ++p) {
        int fid = tid + p * 256;
        int r = fid / 48, c4 = (fid % 48) * 4;
        float4 a4 = *(const float4*)&x[(size_t)(row0 + r) * 192 + c4];
        uint2 pk;
        pk.x = pack2bf(a4.x, a4.y);
        pk.y = pack2bf(a4.z, a4.w);
        *(uint2*)&alds[r][c4] = pk;
    }

    f32x4 acc[4];
    #pragma unroll
    for (int nt = 0; nt < 4; ++nt) acc[nt] = (f32x4){0.f, 0.f, 0.f, 0.f};

    for (int k0 = 0; k0 < 192; k0 += 64) {
        __syncthreads();
        #pragma unroll
        for (int p = 0; p < 4; ++p) {
            int fid = tid + p * 256;
            int j = fid >> 4, k4 = (fid & 15) * 4;
            float4 w4 = *(const float4*)&w[(size_t)(col0 + j) * 192 + k0 + k4];
            uint2 pk;
            pk.x = pack2bf(w4.x, w4.y);
            pk.y = pack2bf(w4.z, w4.w);
            *(uint2*)&blds[j][k4] = pk;
        }
        __syncthreads();
        #pragma unroll
        for (int ks = 0; ks < 2; ++ks) {
            bf16x8 af = *(const bf16x8*)&alds[wv * 16 + qi][k0 + ks * 32 + g * 8];
            #pragma unroll
            for (int nt = 0; nt < 4; ++nt) {
                bf16x8 bf = *(const bf16x8*)&blds[nt * 16 + qi][ks * 32 + g * 8];
                acc[nt] = __builtin_amdgcn_mfma_f32_16x16x32_bf16(af, bf, acc[nt], 0, 0, 0);
            }
        }
    }

    #pragma unroll
    for (int nt = 0; nt < 4; ++nt) {
        int col = col0 + nt * 16 + qi;
        int three = col / 192;
        int rem = col - three * 192;
        int h = rem >> 5, c = rem & 31;
        unsigned short* dst = (three == 0) ? qout : ((three == 1) ? kout : vout);
        float scl = (three == 0) ? SC2F : 1.0f;
        #pragma unroll
        for (int r = 0; r < 4; ++r) {
            int row = row0 + wv * 16 + 4 * g + r;
            int n = row / 1600, t = row - n * 1600;
            dst[((size_t)(n * 6 + h) * 1600 + t) * 32 + c] = f2bf(acc[nt][r] * scl);
        }
    }
}

// ---------------------------------------------------------------------------
// Kernel 2: fused attention. Role-split staging (waves 0-1: K, waves 2-3: V
// s-pair-packed u32 transpose), double-buffered, table aug-frags, packed ttl
// tables, no-max exp2 softmax, LDS P-redistribute.
// ---------------------------------------------------------------------------
__global__ __launch_bounds__(256) void attn_kernel(
    const unsigned short* __restrict__ qw, const unsigned short* __restrict__ kw,
    const unsigned short* __restrict__ vw, const float* __restrict__ th,
    const int* __restrict__ hops, const unsigned int* __restrict__ augA,
    const unsigned int* __restrict__ g_tthi, const unsigned int* __restrict__ g_ttlo,
    const float* __restrict__ alpha_p, float* __restrict__ aout)
{
    __shared__ __align__(16) unsigned short ks[2][64][40];   // K, padded rows
    __shared__ __align__(16) unsigned int vts32[2][32][34];  // V^T, s-pair packed
    __shared__ __align__(16) unsigned int plds[4][16][36];   // per-wave P buffer
    __shared__ unsigned int tthi[127], ttlo[127];

    int b = blockIdx.x;
    int serial = (b & 7) * 150 + (b >> 3);   // XCD-contiguous nh chunks
    int nh = serial / 25;
    int qt = serial % 25;
    int h = nh % 6;
    int t0 = qt * 64;

    int tid = threadIdx.x;
    int lane = tid & 63, wv = tid >> 6;
    int g = lane >> 4, qi = lane & 15;
    int i = tid & 127;
    bool isK = (wv < 2);

    const unsigned short* qb = qw + (size_t)nh * 51200;
    const unsigned short* kb = kw + (size_t)nh * 51200;
    const unsigned short* vb = vw + (size_t)nh * 51200;
    float* ab = aout + (size_t)nh * 51200;

    if (tid < 127) {
        tthi[tid] = g_tthi[h * 127 + tid];
        ttlo[tid] = g_ttlo[h * 127 + tid];
    }

    int tq = t0 + wv * 16 + qi;
    int ft = (tq * 5243) >> 17;
    int pt = tq - ft * 25;

    bf16x8 qfrag = *(const bf16x8*)&qb[(size_t)tq * 32 + g * 8];

    // static part of B_aug (hop bias, pre-scaled th), hi+lo split
    unsigned int baug_hi[4], baug_lo[4];
    #pragma unroll
    for (int jj = 0; jj < 4; ++jj) {
        int k0 = g * 8 + 2 * jj, k1 = k0 + 1;
        float v0 = 0.f, v1 = 0.f;
        if (k0 >= 4 && k0 < 29) v0 = th[h * 5 + hops[pt * 25 + (k0 - 4)]];
        if (k1 >= 4 && k1 < 29) v1 = th[h * 5 + hops[pt * 25 + (k1 - 4)]];
        unsigned short h0 = f2bf(v0), h1 = f2bf(v1);
        unsigned short l0 = f2bf(v0 - bf2f(h0)), l1 = f2bf(v1 - bf2f(h1));
        baug_hi[jj] = (unsigned)h0 | ((unsigned)h1 << 16);
        baug_lo[jj] = (unsigned)l0 | ((unsigned)l1 << 16);
    }

    float l = 0.f;
    f32x4 O0 = {0.f, 0.f, 0.f, 0.f}, O1 = {0.f, 0.f, 0.f, 0.f};

    const uint4v* augp = (const uint4v*)augA;

    // ---- prologue: stage tile 0 into buffer 0 ----
    if (isK) {
        int row = i >> 1, c16 = (i & 1) * 16;
        const unsigned short* src = kb + (size_t)row * 32 + c16;
        uint4 a = *(const uint4*)src;
        uint4 bq = *(const uint4*)(src + 8);
        *(uint4*)&ks[0][row][c16] = a;
        *(uint4*)&ks[0][row][c16 + 8] = bq;
    } else {
        int p = i >> 2, c8v = (i & 3) * 8;
        const unsigned short* src = vb + (size_t)(2 * p) * 32 + c8v;
        union { uint4 u; unsigned short s[8]; } a, bq;
        a.u = *(const uint4*)src;
        bq.u = *(const uint4*)(src + 32);
        #pragma unroll
        for (int j = 0; j < 8; ++j)
            vts32[0][c8v + j][p] = (unsigned)a.s[j] | ((unsigned)bq.s[j] << 16);
    }
    uint4v augr[4];
    #pragma unroll
    for (int sb = 0; sb < 4; ++sb) augr[sb] = augp[(size_t)sb * 64 + lane];
    __syncthreads();

    for (int tau = 0; tau < 25; ++tau) {
        int cur = tau & 1, nxt = cur ^ 1;
        int s0 = tau * 64;
        bool more = (tau < 24);

        // issue next tile's loads early
        uint4 r0 = {0, 0, 0, 0}, r1 = {0, 0, 0, 0};
        uint4v augn[4];
        if (more) {
            if (isK) {
                int row = i >> 1, c16 = (i & 1) * 16;
                const unsigned short* src = kb + (size_t)(s0 + 64 + row) * 32 + c16;
                r0 = *(const uint4*)src;
                r1 = *(const uint4*)(src + 8);
            } else {
                int p = i >> 2, c8v = (i & 3) * 8;
                const unsigned short* src = vb + (size_t)(s0 + 64 + 2 * p) * 32 + c8v;
                r0 = *(const uint4*)src;
                r1 = *(const uint4*)(src + 32);
            }
            #pragma unroll
            for (int sb = 0; sb < 4; ++sb)
                augn[sb] = augp[(size_t)((tau + 1) * 4 + sb) * 64 + lane];
        }

        int fs0 = (s0 * 5243) >> 17;

        // dynamic ttl slots of B_aug from packed tables (g==0 lanes)
        unsigned int bh0 = baug_hi[0], bh1 = baug_hi[1];
        unsigned int bl0 = baug_lo[0], bl1 = baug_lo[1];
        if (g == 0) {
            int base = ft - fs0 + 63;
            bh0 = tthi[base]; bh1 = tthi[base - 2];
            bl0 = ttlo[base]; bl1 = ttlo[base - 2];
        }
        uint4v bhiu = {bh0, bh1, baug_hi[2], baug_hi[3]};
        uint4v blou = {bl0, bl1, baug_lo[2], baug_lo[3]};
        bf16x8 bhif = __builtin_bit_cast(bf16x8, bhiu);
        bf16x8 blof = __builtin_bit_cast(bf16x8, blou);

        // QK^T + bias via table-driven aug-MFMA
        f32x4 sfr[4];
        #pragma unroll
        for (int sb = 0; sb < 4; ++sb) {
            bf16x8 af = __builtin_bit_cast(bf16x8, augr[sb]);
            bf16x8 kf = *(const bf16x8*)&ks[cur][sb * 16 + qi][g * 8];
            f32x4 cz = {0.f, 0.f, 0.f, 0.f};
            f32x4 cb = __builtin_amdgcn_mfma_f32_16x16x32_bf16(af, blof, cz, 0, 0, 0);
            cb = __builtin_amdgcn_mfma_f32_16x16x32_bf16(af, bhif, cb, 0, 0, 0);
            sfr[sb] = __builtin_amdgcn_mfma_f32_16x16x32_bf16(kf, qfrag, cb, 0, 0, 0);
        }

        // unnormalized softmax: p = 2^sfr (logits already in log2 units)
        #pragma unroll
        for (int sb = 0; sb < 4; ++sb) {
            float p0 = __builtin_exp2f(sfr[sb][0]);
            float p1 = __builtin_exp2f(sfr[sb][1]);
            float p2 = __builtin_exp2f(sfr[sb][2]);
            float p3 = __builtin_exp2f(sfr[sb][3]);
            l += (p0 + p1) + (p2 + p3);
            uint2 wp;
            wp.x = cvt_pk_bf16(p0, p1);
            wp.y = cvt_pk_bf16(p2, p3);
            *(uint2*)&plds[wv][qi][sb * 8 + 2 * g] = wp;
        }

        #pragma unroll
        for (int c = 0; c < 2; ++c) {
            bf16x8 paf = *(const bf16x8*)&plds[wv][qi][c * 16 + 4 * g];
            uint2 la = *(const uint2*)&vts32[cur][qi][c * 16 + 4 * g];
            uint2 lb = *(const uint2*)&vts32[cur][qi][c * 16 + 4 * g + 2];
            uint2 ha = *(const uint2*)&vts32[cur][16 + qi][c * 16 + 4 * g];
            uint2 hb = *(const uint2*)&vts32[cur][16 + qi][c * 16 + 4 * g + 2];
            uint4v u0 = {la.x, la.y, lb.x, lb.y};
            uint4v u1 = {ha.x, ha.y, hb.x, hb.y};
            bf16x8 v0f = __builtin_bit_cast(bf16x8, u0);
            bf16x8 v1f = __builtin_bit_cast(bf16x8, u1);
            O0 = __builtin_amdgcn_mfma_f32_16x16x32_bf16(paf, v0f, O0, 0, 0, 0);
            O1 = __builtin_amdgcn_mfma_f32_16x16x32_bf16(paf, v1f, O1, 0, 0, 0);
        }

        // late LDS writes for tile tau+1
        if (more) {
            if (isK) {
                int row = i >> 1, c16 = (i & 1) * 16;
                *(uint4*)&ks[nxt][row][c16] = r0;
                *(uint4*)&ks[nxt][row][c16 + 8] = r1;
            } else {
                int p = i >> 2, c8v = (i & 3) * 8;
                union { uint4 u; unsigned short s[8]; } a, bq;
                a.u = r0; bq.u = r1;
                #pragma unroll
                for (int j = 0; j < 8; ++j)
                    vts32[nxt][c8v + j][p] = (unsigned)a.s[j] | ((unsigned)bq.s[j] << 16);
            }
            #pragma unroll
            for (int sb = 0; sb < 4; ++sb) augr[sb] = augn[sb];
        }
        __syncthreads();
    }

    l += __shfl_xor(l, 16, 64);
    l += __shfl_xor(l, 32, 64);
    float alpha = alpha_p[0];
    float winv = alpha / l;
    int trow = t0 + wv * 16;
    #pragma unroll
    for (int r = 0; r < 4; ++r) {
        float wr = __uint_as_float(
            __builtin_amdgcn_ds_bpermute((4 * g + r) << 2, __float_as_uint(winv)));
        ab[(size_t)(trow + 4 * g + r) * 32 + qi] = O0[r] * wr;
        ab[(size_t)(trow + 4 * g + r) * 32 + 16 + qi] = O1[r] * wr;
    }
}

// ---------------------------------------------------------------------------
// Kernel 3a: relational term. (unchanged)
// ---------------------------------------------------------------------------
__global__ __launch_bounds__(256) void rel_kernel(
    const float* __restrict__ ab, const unsigned short* __restrict__ vw,
    const float* __restrict__ outer, unsigned short* __restrict__ comb)
{
    __shared__ float olds[25][26];
    __shared__ unsigned short vlds[25][32];
    int b = blockIdx.x;
    int n = b / 384;
    int h = (b / 64) % 6;
    int f = b & 63;
    int tid = threadIdx.x;

    for (int e = tid; e < 625; e += 256) olds[e / 25][e % 25] = outer[h * 625 + e];
    size_t vbase = ((size_t)(n * 6 + h) * 1600 + f * 25) * 32;
    for (int e = tid; e < 400; e += 256)
        ((unsigned int*)&vlds[0][0])[e] = *(const unsigned int*)&vw[vbase + e * 2];
    __syncthreads();

    size_t abase = vbase;
    size_t cbase = ((size_t)n * 1600 + f * 25) * 192 + h * 32;
    for (int e = tid; e < 800; e += 256) {
        int p = e >> 5, c = e & 31;
        float s = ab[abase + e];
        #pragma unroll
        for (int q = 0; q < 25; ++q) s += olds[p][q] * bf2f(vlds[q][c]);
        comb[cbase + (size_t)p * 192 + c] = f2bf(s);
    }
}

// ---------------------------------------------------------------------------
// Kernel 3b: final projection, bf16 MFMA GEMM. (unchanged)
// ---------------------------------------------------------------------------
__global__ __launch_bounds__(256) void proj_gemm_kernel(
    const unsigned short* __restrict__ comb, const float* __restrict__ pw,
    const float* __restrict__ pb, float* __restrict__ out)
{
    __shared__ __align__(16) unsigned short alds[64][200];
    __shared__ __align__(16) unsigned short blds[64][72];

    int b = blockIdx.x;
    int bm = b % 200, bn = b / 200;
    int row0 = bm * 64, col0 = bn * 64;
    int tid = threadIdx.x, lane = tid & 63, wv = tid >> 6;
    int g = lane >> 4, qi = lane & 15;

    #pragma unroll
    for (int p = 0; p < 6; ++p) {
        int fid = tid + p * 256;
        int r = fid / 24, c8 = (fid % 24) * 8;
        *(uint4*)&alds[r][c8] = *(const uint4*)&comb[(size_t)(row0 + r) * 192 + c8];
    }

    f32x4 acc[4];
    #pragma unroll
    for (int nt = 0; nt < 4; ++nt) acc[nt] = (f32x4){0.f, 0.f, 0.f, 0.f};

    for (int k0 = 0; k0 < 192; k0 += 64) {
        __syncthreads();
        #pragma unroll
        for (int p = 0; p < 4; ++p) {
            int fid = tid + p * 256;
            int j = fid >> 4, k4 = (fid & 15) * 4;
            float4 w4 = *(const float4*)&pw[(size_t)(col0 + j) * 192 + k0 + k4];
            uint2 pk;
            pk.x = pack2bf(w4.x, w4.y);
            pk.y = pack2bf(w4.z, w4.w);
            *(uint2*)&blds[j][k4] = pk;
        }
        __syncthreads();
        #pragma unroll
        for (int ks = 0; ks < 2; ++ks) {
            bf16x8 af = *(const bf16x8*)&alds[wv * 16 + qi][k0 + ks * 32 + g * 8];
            #pragma unroll
            for (int nt = 0; nt < 4; ++nt) {
                bf16x8 bf = *(const bf16x8*)&blds[nt * 16 + qi][ks * 32 + g * 8];
                acc[nt] = __builtin_amdgcn_mfma_f32_16x16x32_bf16(af, bf, acc[nt], 0, 0, 0);
            }
        }
    }

    #pragma unroll
    for (int nt = 0; nt < 4; ++nt) {
        int col = col0 + nt * 16 + qi;
        float bias = pb[col];
        #pragma unroll
        for (int r = 0; r < 4; ++r) {
            int row = row0 + wv * 16 + 4 * g + r;
            out[(size_t)row * 192 + col] = acc[nt][r] + bias;
        }
    }
}

// ---------------------------------------------------------------------------
extern "C" void kernel_launch(void* const* d_in, const int* in_sizes, int n_in,
                              void* d_out, int out_size, void* d_ws, size_t ws_size,
                              hipStream_t stream)
{
    const float* x      = (const float*)d_in[0];
    const float* qkv_w  = (const float*)d_in[1];
    const float* proj_w = (const float*)d_in[2];
    const float* proj_b = (const float*)d_in[3];
    const float* t_w1   = (const float*)d_in[4];
    const float* t_b1   = (const float*)d_in[5];
    const float* t_w2   = (const float*)d_in[6];
    const float* t_b2   = (const float*)d_in[7];
    const float* h_w1   = (const float*)d_in[8];
    const float* h_b1   = (const float*)d_in[9];
    const float* h_w2   = (const float*)d_in[10];
    const float* h_b2   = (const float*)d_in[11];
    const float* outer  = (const float*)d_in[12];
    const float* alpha  = (const float*)d_in[13];
    const int*   hops   = (const int*)d_in[14];
    float* out = (float*)d_out;

    char* w8 = (char*)d_ws;
    float* tt = (float*)w8;                                  // 762 f @ 0
    float* th = (float*)(w8 + 3072);                         // 30 f
    unsigned int* g_tthi = (unsigned int*)(w8 + 4096);       // 762 u32
    unsigned int* g_ttlo = (unsigned int*)(w8 + 7168);       // 762 u32
    unsigned int* augA   = (unsigned int*)(w8 + 10240);      // 102400 B
    unsigned short* qb = (unsigned short*)(w8 + 112640);
    unsigned short* kb = qb + 2457600;
    unsigned short* vb = kb + 2457600;
    float* ab = (float*)(w8 + 112640 + 3 * 4915200);
    unsigned short* comb = qb;                               // reuse q buffer

    bias_tables_kernel<<<132, 192, 0, stream>>>(t_w1, t_b1, t_w2, t_b2,
                                                h_w1, h_b1, h_w2, h_b2, tt, th);
    ttpack_kernel<<<6, 128, 0, stream>>>(tt, g_tthi, g_ttlo);
    aug_build_kernel<<<25, 256, 0, stream>>>(augA);
    qkv_gemm_kernel<<<1800, 256, 0, stream>>>(x, qkv_w, qb, kb, vb);
    attn_kernel<<<1200, 256, 0, stream>>>(qb, kb, vb, th, hops, augA,
                                          g_tthi, g_ttlo, alpha, ab);
    rel_kernel<<<3072, 256, 0, stream>>>(ab, vb, outer, comb);
    proj_gemm_kernel<<<600, 256, 0, stream>>>(comb, proj_w, proj_b, out);
}